// Round 1
// baseline (431.216 us; speedup 1.0000x reference)
//
#include <hip/hip_runtime.h>
#include <hip/hip_bf16.h>
#include <math.h>

#define DEV __device__ __forceinline__

typedef __bf16 bf16;
typedef __bf16 bf16x8 __attribute__((ext_vector_type(8)));
typedef __bf16 bf16x4 __attribute__((ext_vector_type(4)));
typedef float f32x4 __attribute__((ext_vector_type(4)));

static constexpr int BATCH = 8, S = 1024, D = 1024, H = 16, HD = 64;
static constexpr int M = BATCH * S;   // 8192 rows in the "token" dimension

DEV f32x4 mfma16(bf16x8 a, bf16x8 b, f32x4 c) {
  return __builtin_amdgcn_mfma_f32_16x16x32_bf16(a, b, c, 0, 0, 0);
}

DEV void gload_lds16(const void* g, void* l) {
  // width-16 global->LDS DMA; LDS dest must be wave-uniform base (+lane*16 implicit)
  __builtin_amdgcn_global_load_lds(
      (__attribute__((address_space(1))) void*)(g),
      (__attribute__((address_space(3))) void*)(l), 16, 0, 0);
}

DEV bf16x8 lds_read8(const void* base, int byteoff) {
  return *(const bf16x8*)((const char*)base + byteoff);
}

// ---------------- elementwise converts ----------------

__global__ void cvt_bf16_kernel(const float* __restrict__ in, bf16* __restrict__ out, int n) {
  int i = (blockIdx.x * blockDim.x + threadIdx.x) * 4;
  int stride = gridDim.x * blockDim.x * 4;
  for (; i < n; i += stride) {
    float4 v = *(const float4*)(in + i);
    bf16x4 o = { (bf16)v.x, (bf16)v.y, (bf16)v.z, (bf16)v.w };
    *(bf16x4*)(out + i) = o;
  }
}

// W [K][N] f32 -> Wt [N][K] bf16  (so GEMM B-fragments read contiguous K)
__global__ void transpose_cvt_kernel(const float* __restrict__ in, bf16* __restrict__ out) {
  __shared__ float t[32][33];
  int n0 = blockIdx.x * 32, k0 = blockIdx.y * 32;
  int tx = threadIdx.x, ty = threadIdx.y;   // block (32,8)
  for (int i = 0; i < 32; i += 8)
    t[ty + i][tx] = in[(size_t)(k0 + ty + i) * D + n0 + tx];
  __syncthreads();
  for (int i = 0; i < 32; i += 8)
    out[(size_t)(n0 + ty + i) * D + k0 + tx] = (bf16)t[tx][ty + i];
}

// ---------------- GEMM: C[M,N] = A[M,K] @ Wt^T + bias ----------------
// m97 structure: 128x128 tile, BK=32, 4 waves each 64x64 (4x4 16x16 frags),
// global_load_lds width 16, 2 barriers per K-step.

template<bool WF32, bool WB16>
__global__ __launch_bounds__(256) void gemm_kernel(
    const bf16* __restrict__ A,    // [Mrows][1024] bf16
    const bf16* __restrict__ Bt,   // [1024][1024] bf16, [n][k]
    const float* __restrict__ bias,
    float* __restrict__ Cf, bf16* __restrict__ Cb)
{
  constexpr int K = 1024, N = 1024, BK = 32;
  __shared__ bf16 As[128 * BK];
  __shared__ bf16 Bs[128 * BK];
  const int tid = threadIdx.x, lane = tid & 63, wave = tid >> 6;
  const int bm = blockIdx.y, bn = blockIdx.x;
  const int wr = wave >> 1, wc = wave & 1;
  f32x4 acc[4][4] = {};
  const char* Ab = (const char*)(A + (size_t)bm * 128 * K);
  const char* Bb = (const char*)(Bt + (size_t)bn * 128 * K);

  for (int kt = 0; kt < K / BK; ++kt) {
    __syncthreads();                       // previous tile's readers done
    const int k0b = kt * (BK * 2);         // byte offset within a K-row
    for (int i = 0; i < 2; ++i) {
      int cbase = (wave * 2 + i) * 1024;   // 1KB chunk per wave-issue
      int off = cbase + lane * 16;         // byte within 8KB tile, rows of 64B
      int row = off >> 6, col = off & 63;
      gload_lds16(Ab + (size_t)row * (K * 2) + k0b + col, (char*)As + cbase);
      gload_lds16(Bb + (size_t)row * (K * 2) + k0b + col, (char*)Bs + cbase);
    }
    __syncthreads();                       // staging complete (vmcnt drained)
    bf16x8 af[4], bfr[4];
    for (int mi = 0; mi < 4; ++mi)
      af[mi] = lds_read8(As, (wr * 64 + mi * 16 + (lane & 15)) * 64 + (lane >> 4) * 16);
    for (int ni = 0; ni < 4; ++ni)
      bfr[ni] = lds_read8(Bs, (wc * 64 + ni * 16 + (lane & 15)) * 64 + (lane >> 4) * 16);
    for (int mi = 0; mi < 4; ++mi)
      for (int ni = 0; ni < 4; ++ni)
        acc[mi][ni] = mfma16(af[mi], bfr[ni], acc[mi][ni]);
  }

  const int rbase = bm * 128 + wr * 64;
  const int cbase = bn * 128 + wc * 64;
  for (int ni = 0; ni < 4; ++ni) {
    int col = cbase + ni * 16 + (lane & 15);
    float bv = bias[col];
    for (int mi = 0; mi < 4; ++mi) {
      int row0 = rbase + mi * 16 + (lane >> 4) * 4;
      for (int r = 0; r < 4; ++r) {
        float v = acc[mi][ni][r] + bv;
        size_t idx = (size_t)(row0 + r) * N + col;
        if (WF32) Cf[idx] = v;
        if (WB16) Cb[idx] = (bf16)v;
      }
    }
  }
}

// ---------------- flash attention ----------------
// grid (Sq/64, B*H); 4 waves/block, wave handles 16 q-rows; KVBLK=64.
// K_lds [kv][hd], Vt_lds [hd][kv], both XOR-swizzled (row&7)<<4 on byte addr.

DEV int swz(int row, int colb) { return row * 128 + (colb ^ ((row & 7) << 4)); }

__global__ __launch_bounds__(256) void attn_kernel(
    const bf16* __restrict__ q, const bf16* __restrict__ k, const bf16* __restrict__ v,
    const int* __restrict__ mask, float* __restrict__ ctx)
{
  __shared__ bf16 Kl[64 * 64];
  __shared__ bf16 Vt[64 * 64];
  __shared__ bf16 Pl[4][16 * 64];
  const int tid = threadIdx.x, lane = tid & 63, wave = tid >> 6;
  const int qt = blockIdx.x;
  const int bh = blockIdx.y, b = bh >> 4, h = bh & 15;
  const int q0 = qt * 64 + wave * 16;
  const size_t base = (size_t)b * S * D + (size_t)h * HD;

  bf16x8 qf[2];
  for (int c = 0; c < 2; ++c) {
    int row = q0 + (lane & 15);
    int hd = c * 32 + (lane >> 4) * 8;
    qf[c] = *(const bf16x8*)(q + base + (size_t)row * D + hd);
  }
  f32x4 oacc[4] = {};
  float mrow[4], lrow[4];
  for (int r = 0; r < 4; ++r) { mrow[r] = -1e30f; lrow[r] = 0.f; }

  for (int kt = 0; kt < S / 64; ++kt) {
    const int kv0 = kt * 64;
    __syncthreads();
    // stage K tile [kv][hd], reg-staged (swizzle), b128 writes
    for (int rr = 0; rr < 2; ++rr) {
      int off = (rr * 256 + tid) * 16;     // rows of 128B
      int row = off >> 7, colb = off & 127;
      bf16x8 val = *(const bf16x8*)((const char*)(k + base + (size_t)(kv0 + row) * D) + colb);
      *(bf16x8*)((char*)Kl + swz(row, colb)) = val;
    }
    // stage V transposed: lane = hd column; coalesced 128B global rows
    for (int rr = 0; rr < 2; ++rr) {
      int kvr = rr * 32 + wave * 8;
      bf16x8 val;
      for (int i = 0; i < 8; ++i)
        val[i] = v[base + (size_t)(kv0 + kvr + i) * D + lane];
      *(bf16x8*)((char*)Vt + swz(lane, kvr * 2)) = val;
    }
    __syncthreads();

    // QK^T: S[16 q][64 kv] in 4 col-tiles
    f32x4 sacc[4];
    for (int ct = 0; ct < 4; ++ct) {
      sacc[ct] = (f32x4){0.f, 0.f, 0.f, 0.f};
      for (int c = 0; c < 2; ++c) {
        int row = ct * 16 + (lane & 15);
        bf16x8 kf = *(const bf16x8*)((const char*)Kl + swz(row, c * 64 + (lane >> 4) * 16));
        sacc[ct] = mfma16(qf[c], kf, sacc[ct]);
      }
    }
    // scale + mask + row-max
    float sv[4][4], mx[4];
    for (int r = 0; r < 4; ++r) mx[r] = -1e30f;
    for (int ct = 0; ct < 4; ++ct) {
      int col = kv0 + ct * 16 + (lane & 15);
      bool ok = mask[b * S + col] != 0;
      for (int r = 0; r < 4; ++r) {
        float sc = ok ? sacc[ct][r] * 0.125f : -1e30f;
        sv[ct][r] = sc;
        mx[r] = fmaxf(mx[r], sc);
      }
    }
    for (int off = 1; off < 16; off <<= 1)
      for (int r = 0; r < 4; ++r)
        mx[r] = fmaxf(mx[r], __shfl_xor(mx[r], off));
    float fsc[4], rsum[4];
    for (int r = 0; r < 4; ++r) {
      float mnew = fmaxf(mrow[r], mx[r]);
      fsc[r] = __expf(mrow[r] - mnew);
      mrow[r] = mnew;
      rsum[r] = 0.f;
    }
    // P = exp(S - m), bf16 -> per-wave LDS [q][kv] swizzled
    for (int ct = 0; ct < 4; ++ct) {
      for (int r = 0; r < 4; ++r) {
        float p = __expf(sv[ct][r] - mrow[r]);
        rsum[r] += p;
        int row = (lane >> 4) * 4 + r;
        int colb = (ct * 16 + (lane & 15)) * 2;
        *(bf16*)((char*)Pl[wave] + swz(row, colb)) = (bf16)p;
      }
    }
    for (int off = 1; off < 16; off <<= 1)
      for (int r = 0; r < 4; ++r)
        rsum[r] += __shfl_xor(rsum[r], off);
    for (int r = 0; r < 4; ++r)
      lrow[r] = lrow[r] * fsc[r] + rsum[r];
    for (int od = 0; od < 4; ++od)
      for (int r = 0; r < 4; ++r)
        oacc[od][r] *= fsc[r];
    // PV: O[16 q][64 hd]
    bf16x8 pf[2];
    for (int c = 0; c < 2; ++c)
      pf[c] = *(const bf16x8*)((const char*)Pl[wave] + swz(lane & 15, c * 64 + (lane >> 4) * 16));
    for (int od = 0; od < 4; ++od) {
      for (int c = 0; c < 2; ++c) {
        int row = od * 16 + (lane & 15);  // hd
        bf16x8 vf = *(const bf16x8*)((const char*)Vt + swz(row, c * 64 + (lane >> 4) * 16));
        oacc[od] = mfma16(pf[c], vf, oacc[od]);
      }
    }
  }
  for (int r = 0; r < 4; ++r) {
    int row = q0 + (lane >> 4) * 4 + r;
    float inv = 1.0f / lrow[r];
    for (int od = 0; od < 4; ++od) {
      int col = od * 16 + (lane & 15);
      ctx[((size_t)b * S + row) * D + h * HD + col] = oacc[od][r] * inv;
    }
  }
}

// ---------------- LayerNorms ----------------

DEV void block_stats(float s, float s2, float* red, int tid, float& mu, float& rstd) {
  for (int off = 32; off > 0; off >>= 1) {
    s += __shfl_down(s, off);
    s2 += __shfl_down(s2, off);
  }
  int wave = tid >> 6, lane = tid & 63;
  if (lane == 0) { red[wave] = s; red[4 + wave] = s2; }
  __syncthreads();
  float S1 = red[0] + red[1] + red[2] + red[3];
  float S2 = red[4] + red[5] + red[6] + red[7];
  mu = S1 * (1.f / 1024.f);
  rstd = rsqrtf(S2 * (1.f / 1024.f) - mu * mu + 1e-5f);
}

__global__ __launch_bounds__(256) void ln0_kernel(
    const float* __restrict__ qf, const float* __restrict__ ctx,
    const float* __restrict__ g, const float* __restrict__ beta,
    float* __restrict__ of, bf16* __restrict__ ob)
{
  __shared__ float red[8];
  const int row = blockIdx.x, tid = threadIdx.x;
  const size_t base = (size_t)row * D;
  float4 x = *(const float4*)(qf + base + tid * 4);
  float4 c = *(const float4*)(ctx + base + tid * 4);
  x.x += c.x; x.y += c.y; x.z += c.z; x.w += c.w;
  float mu, rstd;
  block_stats(x.x + x.y + x.z + x.w,
              x.x * x.x + x.y * x.y + x.z * x.z + x.w * x.w, red, tid, mu, rstd);
  float4 gv = *(const float4*)(g + tid * 4);
  float4 bv = *(const float4*)(beta + tid * 4);
  float o0 = (x.x - mu) * rstd * gv.x + bv.x;
  float o1 = (x.y - mu) * rstd * gv.y + bv.y;
  float o2 = (x.z - mu) * rstd * gv.z + bv.z;
  float o3 = (x.w - mu) * rstd * gv.w + bv.w;
  *(float4*)(of + base + tid * 4) = make_float4(o0, o1, o2, o3);
  bf16x4 o = { (bf16)o0, (bf16)o1, (bf16)o2, (bf16)o3 };
  *(bf16x4*)(ob + base + tid * 4) = o;
}

DEV float gelu_exact(float t) { return 0.5f * t * (1.f + erff(t * 0.70710678118654752f)); }

__global__ __launch_bounds__(256) void ln1_kernel(
    const float* __restrict__ of, const float* __restrict__ pf,
    const float* __restrict__ g, const float* __restrict__ beta,
    float* __restrict__ out)
{
  __shared__ float red[8];
  const int row = blockIdx.x, tid = threadIdx.x;
  const size_t base = (size_t)row * D;
  float4 x = *(const float4*)(of + base + tid * 4);
  float4 p = *(const float4*)(pf + base + tid * 4);
  x.x += gelu_exact(p.x); x.y += gelu_exact(p.y);
  x.z += gelu_exact(p.z); x.w += gelu_exact(p.w);
  float mu, rstd;
  block_stats(x.x + x.y + x.z + x.w,
              x.x * x.x + x.y * x.y + x.z * x.z + x.w * x.w, red, tid, mu, rstd);
  float4 gv = *(const float4*)(g + tid * 4);
  float4 bv = *(const float4*)(beta + tid * 4);
  float o0 = (x.x - mu) * rstd * gv.x + bv.x;
  float o1 = (x.y - mu) * rstd * gv.y + bv.y;
  float o2 = (x.z - mu) * rstd * gv.z + bv.z;
  float o3 = (x.w - mu) * rstd * gv.w + bv.w;
  *(float4*)(out + base + tid * 4) = make_float4(o0, o1, o2, o3);
}

// ---------------- launch ----------------

extern "C" void kernel_launch(void* const* d_in, const int* in_sizes, int n_in,
                              void* d_out, int out_size, void* d_ws, size_t ws_size,
                              hipStream_t stream) {
  const float* Q     = (const float*)d_in[0];
  const float* K     = (const float*)d_in[1];
  const int*   mask  = (const int*)d_in[2];
  const float* Wq    = (const float*)d_in[3];
  const float* bq    = (const float*)d_in[4];
  const float* Wk    = (const float*)d_in[5];
  const float* bk    = (const float*)d_in[6];
  const float* Wv    = (const float*)d_in[7];
  const float* bv    = (const float*)d_in[8];
  const float* Wp    = (const float*)d_in[9];
  const float* bp    = (const float*)d_in[10];
  const float* g0    = (const float*)d_in[11];
  const float* beta0 = (const float*)d_in[12];
  const float* g1    = (const float*)d_in[13];
  const float* beta1 = (const float*)d_in[14];
  float* out = (float*)d_out;

  char* w = (char*)d_ws;
  const size_t MB = 1u << 20;
  bf16* Qb  = (bf16*)(w + 0 * MB);        // 16MB, dead after GEMM1 (q)
  bf16* Kb  = (bf16*)(w + 16 * MB);       // 16MB
  bf16* Wqt = (bf16*)(w + 32 * MB);       // 2MB each
  bf16* Wkt = (bf16*)(w + 34 * MB);
  bf16* Wvt = (bf16*)(w + 36 * MB);
  bf16* Wpt = (bf16*)(w + 38 * MB);
  float* qf = (float*)(w + 40 * MB);      // 32MB
  bf16* qb  = (bf16*)(w + 72 * MB);       // 16MB
  bf16* kb  = (bf16*)(w + 88 * MB);       // 16MB
  bf16* vb  = (bf16*)(w + 104 * MB);      // 16MB
  float* ctx = (float*)(w + 120 * MB);    // 32MB; p aliases after LN0
  float* pf  = ctx;
  float* of  = (float*)(w + 152 * MB);    // 32MB   (total 184MB)
  bf16* ob   = (bf16*)(w + 0 * MB);       // alias Qb

  cvt_bf16_kernel<<<2048, 256, 0, stream>>>(Q, Qb, M * D);
  cvt_bf16_kernel<<<2048, 256, 0, stream>>>(K, Kb, M * D);
  dim3 tb(32, 8), tg(32, 32);
  transpose_cvt_kernel<<<tg, tb, 0, stream>>>(Wq, Wqt);
  transpose_cvt_kernel<<<tg, tb, 0, stream>>>(Wk, Wkt);
  transpose_cvt_kernel<<<tg, tb, 0, stream>>>(Wv, Wvt);
  transpose_cvt_kernel<<<tg, tb, 0, stream>>>(Wp, Wpt);

  dim3 gg(D / 128, M / 128);  // (8, 64)
  gemm_kernel<true,  true ><<<gg, 256, 0, stream>>>(Qb, Wqt, bq, qf, qb);
  gemm_kernel<false, true ><<<gg, 256, 0, stream>>>(Kb, Wkt, bk, nullptr, kb);
  gemm_kernel<false, true ><<<gg, 256, 0, stream>>>(Kb, Wvt, bv, nullptr, vb);

  dim3 ag(S / 64, BATCH * H);  // (16, 128)
  attn_kernel<<<ag, 256, 0, stream>>>(qb, kb, vb, mask, ctx);

  ln0_kernel<<<M, 256, 0, stream>>>(qf, ctx, g0, beta0, of, ob);
  gemm_kernel<true, false><<<gg, 256, 0, stream>>>(ob, Wpt, bp, pf, nullptr);
  ln1_kernel<<<M, 256, 0, stream>>>(of, pf, g1, beta1, out);
}

// Round 2
// 405.771 us; speedup vs baseline: 1.0627x; 1.0627x over previous
//
#include <hip/hip_runtime.h>
#include <hip/hip_bf16.h>
#include <math.h>

#define DEV __device__ __forceinline__

typedef __bf16 bf16;
typedef __bf16 bf16x8 __attribute__((ext_vector_type(8)));
typedef __bf16 bf16x4 __attribute__((ext_vector_type(4)));
typedef float f32x4 __attribute__((ext_vector_type(4)));

static constexpr int BATCH = 8, S = 1024, D = 1024, H = 16, HD = 64;
static constexpr int M = BATCH * S;   // 8192 rows in the "token" dimension

DEV f32x4 mfma16(bf16x8 a, bf16x8 b, f32x4 c) {
  return __builtin_amdgcn_mfma_f32_16x16x32_bf16(a, b, c, 0, 0, 0);
}

DEV void gload_lds16(const void* g, void* l) {
  __builtin_amdgcn_global_load_lds(
      (__attribute__((address_space(1))) void*)(g),
      (__attribute__((address_space(3))) void*)(l), 16, 0, 0);
}

DEV bf16x8 lds_read8(const void* base, int byteoff) {
  return *(const bf16x8*)((const char*)base + byteoff);
}

// ---------------- elementwise converts ----------------

__global__ void cvt_bf16_kernel(const float* __restrict__ in, bf16* __restrict__ out, int n) {
  int i = (blockIdx.x * blockDim.x + threadIdx.x) * 4;
  int stride = gridDim.x * blockDim.x * 4;
  for (; i < n; i += stride) {
    float4 v = *(const float4*)(in + i);
    bf16x4 o = { (bf16)v.x, (bf16)v.y, (bf16)v.z, (bf16)v.w };
    *(bf16x4*)(out + i) = o;
  }
}

// W [K][N] f32 -> Wt [N][K] bf16
__global__ void transpose_cvt_kernel(const float* __restrict__ in, bf16* __restrict__ out) {
  __shared__ float t[32][33];
  int n0 = blockIdx.x * 32, k0 = blockIdx.y * 32;
  int tx = threadIdx.x, ty = threadIdx.y;   // block (32,8)
  for (int i = 0; i < 32; i += 8)
    t[ty + i][tx] = in[(size_t)(k0 + ty + i) * D + n0 + tx];
  __syncthreads();
  for (int i = 0; i < 32; i += 8)
    out[(size_t)(n0 + ty + i) * D + k0 + tx] = (bf16)t[tx][ty + i];
}

// ---------------- GEMM (m97 structure, unchanged) ----------------

template<bool WF32, bool WB16>
__global__ __launch_bounds__(256) void gemm_kernel(
    const bf16* __restrict__ A, const bf16* __restrict__ Bt,
    const float* __restrict__ bias,
    float* __restrict__ Cf, bf16* __restrict__ Cb)
{
  constexpr int K = 1024, N = 1024, BK = 32;
  __shared__ bf16 As[128 * BK];
  __shared__ bf16 Bs[128 * BK];
  const int tid = threadIdx.x, lane = tid & 63, wave = tid >> 6;
  const int bm = blockIdx.y, bn = blockIdx.x;
  const int wr = wave >> 1, wc = wave & 1;
  f32x4 acc[4][4] = {};
  const char* Ab = (const char*)(A + (size_t)bm * 128 * K);
  const char* Bb = (const char*)(Bt + (size_t)bn * 128 * K);

  for (int kt = 0; kt < K / BK; ++kt) {
    __syncthreads();
    const int k0b = kt * (BK * 2);
    for (int i = 0; i < 2; ++i) {
      int cbase = (wave * 2 + i) * 1024;
      int off = cbase + lane * 16;
      int row = off >> 6, col = off & 63;
      gload_lds16(Ab + (size_t)row * (K * 2) + k0b + col, (char*)As + cbase);
      gload_lds16(Bb + (size_t)row * (K * 2) + k0b + col, (char*)Bs + cbase);
    }
    __syncthreads();
    bf16x8 af[4], bfr[4];
    for (int mi = 0; mi < 4; ++mi)
      af[mi] = lds_read8(As, (wr * 64 + mi * 16 + (lane & 15)) * 64 + (lane >> 4) * 16);
    for (int ni = 0; ni < 4; ++ni)
      bfr[ni] = lds_read8(Bs, (wc * 64 + ni * 16 + (lane & 15)) * 64 + (lane >> 4) * 16);
    for (int mi = 0; mi < 4; ++mi)
      for (int ni = 0; ni < 4; ++ni)
        acc[mi][ni] = mfma16(af[mi], bfr[ni], acc[mi][ni]);
  }

  const int rbase = bm * 128 + wr * 64;
  const int cbase = bn * 128 + wc * 64;
  for (int ni = 0; ni < 4; ++ni) {
    int col = cbase + ni * 16 + (lane & 15);
    float bv = bias[col];
    for (int mi = 0; mi < 4; ++mi) {
      int row0 = rbase + mi * 16 + (lane >> 4) * 4;
      for (int r = 0; r < 4; ++r) {
        float v = acc[mi][ni][r] + bv;
        size_t idx = (size_t)(row0 + r) * N + col;
        if (WF32) Cf[idx] = v;
        if (WB16) Cb[idx] = (bf16)v;
      }
    }
  }
}

// ---------------- flash attention (swapped QK^T, in-register softmax) ----------------
// grid (Sq/128, B*H); 4 waves/block, wave = 32 q rows (2 qsets of 16); KVBLK=64.
// S^T = mfma(K, Q): lane holds 16 kv scores for q = lane&15  ->  local reduce
// + 2 shfl_xor; P packed as 4x ds_write_b64 (swizzled); PV via Vt as before.

DEV int swz(int row, int colb) { return row * 128 + (colb ^ ((row & 7) << 4)); }

__global__ __launch_bounds__(256) void attn_kernel(
    const bf16* __restrict__ q, const bf16* __restrict__ k, const bf16* __restrict__ v,
    const int* __restrict__ mask, float* __restrict__ ctx)
{
  __shared__ bf16 Kl[64 * 64];
  __shared__ bf16 Vt[64 * 64];
  __shared__ bf16 Pl[4][2][16 * 64];
  const int tid = threadIdx.x, lane = tid & 63, wave = tid >> 6;
  const int g = lane >> 4, lo = lane & 15;
  const int bh = blockIdx.y, b = bh >> 4, h = bh & 15;
  const int q0w = blockIdx.x * 128 + wave * 32;
  const size_t base = (size_t)b * S * D + (size_t)h * HD;

  // Q fragments: qf[qset][c], lane lo <-> q row, 8 hd elems at g*8 + c*32
  bf16x8 qf[2][2];
#pragma unroll
  for (int qs = 0; qs < 2; ++qs)
#pragma unroll
    for (int c = 0; c < 2; ++c)
      qf[qs][c] = *(const bf16x8*)(q + base + (size_t)(q0w + qs * 16 + lo) * D + c * 32 + g * 8);

  f32x4 oacc[2][4] = {};
  float mrow[2] = {-1e30f, -1e30f}, lrow[2] = {0.f, 0.f};

  for (int kt = 0; kt < S / 64; ++kt) {
    const int kv0 = kt * 64;
    __syncthreads();
    // stage K tile [kv][hd] swizzled
#pragma unroll
    for (int rr = 0; rr < 2; ++rr) {
      int off = (rr * 256 + tid) * 16;
      int row = off >> 7, colb = off & 127;
      bf16x8 val = *(const bf16x8*)((const char*)(k + base + (size_t)(kv0 + row) * D) + colb);
      *(bf16x8*)((char*)Kl + swz(row, colb)) = val;
    }
    // stage V transposed [hd][kv] swizzled (lane = hd column)
#pragma unroll
    for (int rr = 0; rr < 2; ++rr) {
      int kvr = rr * 32 + wave * 8;
      bf16x8 val;
#pragma unroll
      for (int i = 0; i < 8; ++i)
        val[i] = v[base + (size_t)(kv0 + kvr + i) * D + lane];
      *(bf16x8*)((char*)Vt + swz(lane, kvr * 2)) = val;
    }
    __syncthreads();

    // K fragments for this tile: kf[ct][c], lane lo <-> kv row within block ct
    bf16x8 kf[4][2];
#pragma unroll
    for (int ct = 0; ct < 4; ++ct)
#pragma unroll
      for (int c = 0; c < 2; ++c)
        kf[ct][c] = lds_read8(Kl, swz(ct * 16 + lo, c * 64 + g * 16));

    // padding mask bits for this tile
    unsigned long long mv = __ballot(mask[b * S + kv0 + lane] != 0);
    unsigned long long mq = mv >> (g * 4);

#pragma unroll
    for (int qs = 0; qs < 2; ++qs) {
      // S^T = mfma(K, Q): col = q (lane lo), row = kv = ct*16 + g*4 + r
      f32x4 sacc[4];
#pragma unroll
      for (int ct = 0; ct < 4; ++ct) {
        sacc[ct] = (f32x4){0.f, 0.f, 0.f, 0.f};
#pragma unroll
        for (int c = 0; c < 2; ++c)
          sacc[ct] = mfma16(kf[ct][c], qf[qs][c], sacc[ct]);
      }
      // scale + mask + local max
      float pv[4][4];
      float mx = -1e30f;
#pragma unroll
      for (int ct = 0; ct < 4; ++ct)
#pragma unroll
        for (int r = 0; r < 4; ++r) {
          float s = sacc[ct][r] * 0.125f;
          bool ok = (mq >> (ct * 16 + r)) & 1ull;
          s = ok ? s : -1e30f;
          pv[ct][r] = s;
          mx = fmaxf(mx, s);
        }
      mx = fmaxf(mx, __shfl_xor(mx, 16));
      mx = fmaxf(mx, __shfl_xor(mx, 32));
      float mnew = fmaxf(mrow[qs], mx);
      float fsc = __expf(mrow[qs] - mnew);
      mrow[qs] = mnew;
      float rs = 0.f;
#pragma unroll
      for (int ct = 0; ct < 4; ++ct)
#pragma unroll
        for (int r = 0; r < 4; ++r) {
          float p = __expf(pv[ct][r] - mnew);
          pv[ct][r] = p;
          rs += p;
        }
      rs += __shfl_xor(rs, 16);
      rs += __shfl_xor(rs, 32);
      lrow[qs] = lrow[qs] * fsc + rs;
      // write P[q][kv] packed b64, swizzled: 4 consecutive kv per lane per ct
      char* Pb = (char*)Pl[wave][qs];
#pragma unroll
      for (int ct = 0; ct < 4; ++ct) {
        bf16x4 w = { (bf16)pv[ct][0], (bf16)pv[ct][1], (bf16)pv[ct][2], (bf16)pv[ct][3] };
        *(bf16x4*)(Pb + lo * 128 + ((ct * 32 + g * 8) ^ ((lo & 7) << 4))) = w;
      }
      // rescale existing accumulator (row domain: q = g*4 + r)
#pragma unroll
      for (int r = 0; r < 4; ++r) {
        float fr = __shfl(fsc, g * 4 + r);
#pragma unroll
        for (int od = 0; od < 4; ++od)
          oacc[qs][od][r] *= fr;
      }
    }

    // PV: read P fragments (a: q rows), Vt fragments (b: hd rows)
    bf16x8 pf[2][2];
#pragma unroll
    for (int qs = 0; qs < 2; ++qs)
#pragma unroll
      for (int c = 0; c < 2; ++c)
        pf[qs][c] = lds_read8(Pl[wave][qs], swz(lo, c * 64 + g * 16));
#pragma unroll
    for (int od = 0; od < 4; ++od) {
      bf16x8 vf0 = lds_read8(Vt, swz(od * 16 + lo, 0 * 64 + g * 16));
      bf16x8 vf1 = lds_read8(Vt, swz(od * 16 + lo, 1 * 64 + g * 16));
#pragma unroll
      for (int qs = 0; qs < 2; ++qs) {
        oacc[qs][od] = mfma16(pf[qs][0], vf0, oacc[qs][od]);
        oacc[qs][od] = mfma16(pf[qs][1], vf1, oacc[qs][od]);
      }
    }
  }

  // epilogue: ctx[q][hd] = oacc / l
#pragma unroll
  for (int qs = 0; qs < 2; ++qs) {
    float linv = 1.0f / lrow[qs];
#pragma unroll
    for (int r = 0; r < 4; ++r) {
      float inv = __shfl(linv, g * 4 + r);
      int row = q0w + qs * 16 + g * 4 + r;
#pragma unroll
      for (int od = 0; od < 4; ++od)
        ctx[((size_t)b * S + row) * D + h * HD + od * 16 + lo] = oacc[qs][od][r] * inv;
    }
  }
}

// ---------------- LayerNorms ----------------

DEV void block_stats(float s, float s2, float* red, int tid, float& mu, float& rstd) {
  for (int off = 32; off > 0; off >>= 1) {
    s += __shfl_down(s, off);
    s2 += __shfl_down(s2, off);
  }
  int wave = tid >> 6, lane = tid & 63;
  if (lane == 0) { red[wave] = s; red[4 + wave] = s2; }
  __syncthreads();
  float S1 = red[0] + red[1] + red[2] + red[3];
  float S2 = red[4] + red[5] + red[6] + red[7];
  mu = S1 * (1.f / 1024.f);
  rstd = rsqrtf(S2 * (1.f / 1024.f) - mu * mu + 1e-5f);
}

__global__ __launch_bounds__(256) void ln0_kernel(
    const float* __restrict__ qf, const float* __restrict__ ctx,
    const float* __restrict__ g, const float* __restrict__ beta,
    float* __restrict__ of, bf16* __restrict__ ob)
{
  __shared__ float red[8];
  const int row = blockIdx.x, tid = threadIdx.x;
  const size_t base = (size_t)row * D;
  float4 x = *(const float4*)(qf + base + tid * 4);
  float4 c = *(const float4*)(ctx + base + tid * 4);
  x.x += c.x; x.y += c.y; x.z += c.z; x.w += c.w;
  float mu, rstd;
  block_stats(x.x + x.y + x.z + x.w,
              x.x * x.x + x.y * x.y + x.z * x.z + x.w * x.w, red, tid, mu, rstd);
  float4 gv = *(const float4*)(g + tid * 4);
  float4 bv = *(const float4*)(beta + tid * 4);
  float o0 = (x.x - mu) * rstd * gv.x + bv.x;
  float o1 = (x.y - mu) * rstd * gv.y + bv.y;
  float o2 = (x.z - mu) * rstd * gv.z + bv.z;
  float o3 = (x.w - mu) * rstd * gv.w + bv.w;
  *(float4*)(of + base + tid * 4) = make_float4(o0, o1, o2, o3);
  bf16x4 o = { (bf16)o0, (bf16)o1, (bf16)o2, (bf16)o3 };
  *(bf16x4*)(ob + base + tid * 4) = o;
}

DEV float gelu_exact(float t) { return 0.5f * t * (1.f + erff(t * 0.70710678118654752f)); }

__global__ __launch_bounds__(256) void ln1_kernel(
    const float* __restrict__ of, const float* __restrict__ pf,
    const float* __restrict__ g, const float* __restrict__ beta,
    float* __restrict__ out)
{
  __shared__ float red[8];
  const int row = blockIdx.x, tid = threadIdx.x;
  const size_t base = (size_t)row * D;
  float4 x = *(const float4*)(of + base + tid * 4);
  float4 p = *(const float4*)(pf + base + tid * 4);
  x.x += gelu_exact(p.x); x.y += gelu_exact(p.y);
  x.z += gelu_exact(p.z); x.w += gelu_exact(p.w);
  float mu, rstd;
  block_stats(x.x + x.y + x.z + x.w,
              x.x * x.x + x.y * x.y + x.z * x.z + x.w * x.w, red, tid, mu, rstd);
  float4 gv = *(const float4*)(g + tid * 4);
  float4 bv = *(const float4*)(beta + tid * 4);
  float o0 = (x.x - mu) * rstd * gv.x + bv.x;
  float o1 = (x.y - mu) * rstd * gv.y + bv.y;
  float o2 = (x.z - mu) * rstd * gv.z + bv.z;
  float o3 = (x.w - mu) * rstd * gv.w + bv.w;
  *(float4*)(out + base + tid * 4) = make_float4(o0, o1, o2, o3);
}

// ---------------- launch ----------------

extern "C" void kernel_launch(void* const* d_in, const int* in_sizes, int n_in,
                              void* d_out, int out_size, void* d_ws, size_t ws_size,
                              hipStream_t stream) {
  const float* Q     = (const float*)d_in[0];
  const float* K     = (const float*)d_in[1];
  const int*   mask  = (const int*)d_in[2];
  const float* Wq    = (const float*)d_in[3];
  const float* bq    = (const float*)d_in[4];
  const float* Wk    = (const float*)d_in[5];
  const float* bk    = (const float*)d_in[6];
  const float* Wv    = (const float*)d_in[7];
  const float* bv    = (const float*)d_in[8];
  const float* Wp    = (const float*)d_in[9];
  const float* bp    = (const float*)d_in[10];
  const float* g0    = (const float*)d_in[11];
  const float* beta0 = (const float*)d_in[12];
  const float* g1    = (const float*)d_in[13];
  const float* beta1 = (const float*)d_in[14];
  float* out = (float*)d_out;

  char* w = (char*)d_ws;
  const size_t MB = 1u << 20;
  bf16* Qb  = (bf16*)(w + 0 * MB);
  bf16* Kb  = (bf16*)(w + 16 * MB);
  bf16* Wqt = (bf16*)(w + 32 * MB);
  bf16* Wkt = (bf16*)(w + 34 * MB);
  bf16* Wvt = (bf16*)(w + 36 * MB);
  bf16* Wpt = (bf16*)(w + 38 * MB);
  float* qf = (float*)(w + 40 * MB);
  bf16* qb  = (bf16*)(w + 72 * MB);
  bf16* kb  = (bf16*)(w + 88 * MB);
  bf16* vb  = (bf16*)(w + 104 * MB);
  float* ctx = (float*)(w + 120 * MB);
  float* pf  = ctx;
  float* of  = (float*)(w + 152 * MB);
  bf16* ob   = (bf16*)(w + 0 * MB);   // alias Qb

  cvt_bf16_kernel<<<2048, 256, 0, stream>>>(Q, Qb, M * D);
  cvt_bf16_kernel<<<2048, 256, 0, stream>>>(K, Kb, M * D);
  dim3 tb(32, 8), tg(32, 32);
  transpose_cvt_kernel<<<tg, tb, 0, stream>>>(Wq, Wqt);
  transpose_cvt_kernel<<<tg, tb, 0, stream>>>(Wk, Wkt);
  transpose_cvt_kernel<<<tg, tb, 0, stream>>>(Wv, Wvt);
  transpose_cvt_kernel<<<tg, tb, 0, stream>>>(Wp, Wpt);

  dim3 gg(D / 128, M / 128);
  gemm_kernel<true,  true ><<<gg, 256, 0, stream>>>(Qb, Wqt, bq, qf, qb);
  gemm_kernel<false, true ><<<gg, 256, 0, stream>>>(Kb, Wkt, bk, nullptr, kb);
  gemm_kernel<false, true ><<<gg, 256, 0, stream>>>(Kb, Wvt, bv, nullptr, vb);

  dim3 ag(S / 128, BATCH * H);   // (8, 128)
  attn_kernel<<<ag, 256, 0, stream>>>(qb, kb, vb, mask, ctx);

  ln0_kernel<<<M, 256, 0, stream>>>(qf, ctx, g0, beta0, of, ob);
  gemm_kernel<true, false><<<gg, 256, 0, stream>>>(ob, Wpt, bp, pf, nullptr);
  ln1_kernel<<<M, 256, 0, stream>>>(of, pf, g1, beta1, out);
}

// Round 3
// 381.359 us; speedup vs baseline: 1.1307x; 1.0640x over previous
//
#include <hip/hip_runtime.h>
#include <hip/hip_bf16.h>
#include <math.h>

#define DEV __device__ __forceinline__

typedef __bf16 bf16;
typedef __bf16 bf16x8 __attribute__((ext_vector_type(8)));
typedef __bf16 bf16x4 __attribute__((ext_vector_type(4)));
typedef float f32x4 __attribute__((ext_vector_type(4)));

static constexpr int BATCH = 8, S = 1024, D = 1024, H = 16, HD = 64;
static constexpr int M = BATCH * S;

// 0.125 (1/sqrt(hd)) * log2(e): folded into qb so softmax runs in exp2 domain
static constexpr float QSCALE = 0.18033688f;

DEV f32x4 mfma16(bf16x8 a, bf16x8 b, f32x4 c) {
  return __builtin_amdgcn_mfma_f32_16x16x32_bf16(a, b, c, 0, 0, 0);
}

DEV void gload_lds16(const void* g, void* l) {
  __builtin_amdgcn_global_load_lds(
      (__attribute__((address_space(1))) void*)(g),
      (__attribute__((address_space(3))) void*)(l), 16, 0, 0);
}

DEV bf16x8 lds_read8(const void* base, int byteoff) {
  return *(const bf16x8*)((const char*)base + byteoff);
}

// ---------------- elementwise converts (fused via grid.z) ----------------

__global__ void cvt_bf16_kernel(const float* __restrict__ in0, bf16* __restrict__ out0,
                                const float* __restrict__ in1, bf16* __restrict__ out1, int n) {
  const float* in = blockIdx.y ? in1 : in0;
  bf16* out = blockIdx.y ? out1 : out0;
  int i = (blockIdx.x * blockDim.x + threadIdx.x) * 4;
  int stride = gridDim.x * blockDim.x * 4;
  for (; i < n; i += stride) {
    float4 v = *(const float4*)(in + i);
    bf16x4 o = { (bf16)v.x, (bf16)v.y, (bf16)v.z, (bf16)v.w };
    *(bf16x4*)(out + i) = o;
  }
}

// W [K][N] f32 -> Wt [N][K] bf16; z selects which weight
__global__ void transpose_cvt_kernel(const float* __restrict__ w0, bf16* __restrict__ o0,
                                     const float* __restrict__ w1, bf16* __restrict__ o1,
                                     const float* __restrict__ w2, bf16* __restrict__ o2,
                                     const float* __restrict__ w3, bf16* __restrict__ o3) {
  const int z = blockIdx.z;
  const float* in = z == 0 ? w0 : z == 1 ? w1 : z == 2 ? w2 : w3;
  bf16* out = z == 0 ? o0 : z == 1 ? o1 : z == 2 ? o2 : o3;
  __shared__ float t[32][33];
  int n0 = blockIdx.x * 32, k0 = blockIdx.y * 32;
  int tx = threadIdx.x, ty = threadIdx.y;   // block (32,8)
  for (int i = 0; i < 32; i += 8)
    t[ty + i][tx] = in[(size_t)(k0 + ty + i) * D + n0 + tx];
  __syncthreads();
  for (int i = 0; i < 32; i += 8)
    out[(size_t)(n0 + ty + i) * D + k0 + tx] = (bf16)t[tx][ty + i];
}

// ---------------- GEMM body (m97 structure) ----------------
// XCD swizzle: nwg=512 per matrix, 512%8==0 -> bijective chunked remap.

struct GemmOut { float* f32; bf16* b16; float scale; };

template<int MODE>  // 0: f32 + scaled bf16 (q), 1: bf16 only, 2: f32 only
DEV void gemm_body(const bf16* A, const bf16* Bt, const float* bias,
                   float* Cf, bf16* Cb, float osc,
                   bf16* As, bf16* Bs) {
  constexpr int K = 1024, N = 1024, BK = 32;
  const int tid = threadIdx.x, lane = tid & 63, wave = tid >> 6;
  int f = blockIdx.y * 8 + blockIdx.x;          // gridDim (8,64) -> 512
  f = (f & 7) * 64 + (f >> 3);                  // XCD-chunked, bijective
  const int bm = f >> 3, bn = f & 7;
  const int wr = wave >> 1, wc = wave & 1;
  f32x4 acc[4][4] = {};
  const char* Ab = (const char*)(A + (size_t)bm * 128 * K);
  const char* Bb = (const char*)(Bt + (size_t)bn * 128 * K);

  for (int kt = 0; kt < K / BK; ++kt) {
    __syncthreads();
    const int k0b = kt * (BK * 2);
    for (int i = 0; i < 2; ++i) {
      int cbase = (wave * 2 + i) * 1024;
      int off = cbase + lane * 16;
      int row = off >> 6, col = off & 63;
      gload_lds16(Ab + (size_t)row * (K * 2) + k0b + col, (char*)As + cbase);
      gload_lds16(Bb + (size_t)row * (K * 2) + k0b + col, (char*)Bs + cbase);
    }
    __syncthreads();
    bf16x8 af[4], bfr[4];
    for (int mi = 0; mi < 4; ++mi)
      af[mi] = lds_read8(As, (wr * 64 + mi * 16 + (lane & 15)) * 64 + (lane >> 4) * 16);
    for (int ni = 0; ni < 4; ++ni)
      bfr[ni] = lds_read8(Bs, (wc * 64 + ni * 16 + (lane & 15)) * 64 + (lane >> 4) * 16);
    for (int mi = 0; mi < 4; ++mi)
      for (int ni = 0; ni < 4; ++ni)
        acc[mi][ni] = mfma16(af[mi], bfr[ni], acc[mi][ni]);
  }

  const int rbase = bm * 128 + wr * 64;
  const int cbase = bn * 128 + wc * 64;
  for (int ni = 0; ni < 4; ++ni) {
    int col = cbase + ni * 16 + (lane & 15);
    float bv = bias[col];
    for (int mi = 0; mi < 4; ++mi) {
      int row0 = rbase + mi * 16 + (lane >> 4) * 4;
      for (int r = 0; r < 4; ++r) {
        float v = acc[mi][ni][r] + bv;
        size_t idx = (size_t)(row0 + r) * N + col;
        if (MODE == 0) { Cf[idx] = v; Cb[idx] = (bf16)(v * osc); }
        if (MODE == 1) { Cb[idx] = (bf16)v; }
        if (MODE == 2) { Cf[idx] = v; }
      }
    }
  }
}

__global__ __launch_bounds__(256) void gemm_qkv_kernel(
    const bf16* __restrict__ Qb, const bf16* __restrict__ Kb,
    const bf16* __restrict__ Wqt, const bf16* __restrict__ Wkt, const bf16* __restrict__ Wvt,
    const float* __restrict__ bq, const float* __restrict__ bk, const float* __restrict__ bv,
    float* __restrict__ qf, bf16* __restrict__ qb,
    bf16* __restrict__ kb, bf16* __restrict__ vb)
{
  __shared__ bf16 As[128 * 32];
  __shared__ bf16 Bs[128 * 32];
  const int z = blockIdx.z;
  if (z == 0)      gemm_body<0>(Qb, Wqt, bq, qf, qb, QSCALE, As, Bs);
  else if (z == 1) gemm_body<1>(Kb, Wkt, bk, nullptr, kb, 1.f, As, Bs);
  else             gemm_body<1>(Kb, Wvt, bv, nullptr, vb, 1.f, As, Bs);
}

__global__ __launch_bounds__(256) void gemm_p_kernel(
    const bf16* __restrict__ A, const bf16* __restrict__ Bt,
    const float* __restrict__ bias, float* __restrict__ Cf)
{
  __shared__ bf16 As[128 * 32];
  __shared__ bf16 Bs[128 * 32];
  gemm_body<2>(A, Bt, bias, Cf, nullptr, 1.f, As, Bs);
}

// ---------------- flash attention ----------------
// Swapped QK^T (S^T: q = lane-local), O^T accumulation (q = lane-local again),
// P via stride-144 LDS (2-way banks = free), exp2-domain softmax, defer-max.

DEV int swz(int row, int colb) { return row * 128 + (colb ^ ((row & 7) << 4)); }

__global__ __launch_bounds__(256) void attn_kernel(
    const bf16* __restrict__ q, const bf16* __restrict__ k, const bf16* __restrict__ v,
    const int* __restrict__ mask, float* __restrict__ ctx)
{
  __shared__ bf16 Kl[64 * 64];
  __shared__ bf16 Vt[64 * 64];
  __shared__ bf16 Pl[4][2][16 * 72];   // row stride 144B
  const int tid = threadIdx.x, lane = tid & 63, wave = tid >> 6;
  const int g = lane >> 4, lo = lane & 15;
  const int bh = blockIdx.y, b = bh >> 4, h = bh & 15;
  const int q0w = blockIdx.x * 128 + wave * 32;
  const size_t base = (size_t)b * S * D + (size_t)h * HD;

  bf16x8 qf[2][2];
#pragma unroll
  for (int qs = 0; qs < 2; ++qs)
#pragma unroll
    for (int c = 0; c < 2; ++c)
      qf[qs][c] = *(const bf16x8*)(q + base + (size_t)(q0w + qs * 16 + lo) * D + c * 32 + g * 8);

  f32x4 oaccT[2][4] = {};                       // O^T[hd=od*16+g*4+r][q=lo]
  float mrow[2] = {-1e30f, -1e30f}, lrow[2] = {0.f, 0.f};

  for (int kt = 0; kt < S / 64; ++kt) {
    const int kv0 = kt * 64;
    __syncthreads();
#pragma unroll
    for (int rr = 0; rr < 2; ++rr) {            // K tile [kv][hd], swizzled
      int off = (rr * 256 + tid) * 16;
      int row = off >> 7, colb = off & 127;
      bf16x8 val = *(const bf16x8*)((const char*)(k + base + (size_t)(kv0 + row) * D) + colb);
      *(bf16x8*)((char*)Kl + swz(row, colb)) = val;
    }
#pragma unroll
    for (int rr = 0; rr < 2; ++rr) {            // V transposed [hd][kv], swizzled
      int kvr = rr * 32 + wave * 8;
      bf16x8 val;
#pragma unroll
      for (int i = 0; i < 8; ++i)
        val[i] = v[base + (size_t)(kv0 + kvr + i) * D + lane];
      *(bf16x8*)((char*)Vt + swz(lane, kvr * 2)) = val;
    }
    __syncthreads();

    bf16x8 kf[4][2];
#pragma unroll
    for (int ct = 0; ct < 4; ++ct)
#pragma unroll
      for (int c = 0; c < 2; ++c)
        kf[ct][c] = lds_read8(Kl, swz(ct * 16 + lo, c * 64 + g * 16));

    unsigned long long mv = __ballot(mask[b * S + kv0 + lane] != 0);
    unsigned long long mq = mv >> (g * 4);

#pragma unroll
    for (int qs = 0; qs < 2; ++qs) {
      f32x4 sacc[4];
#pragma unroll
      for (int ct = 0; ct < 4; ++ct) {
        sacc[ct] = (f32x4){0.f, 0.f, 0.f, 0.f};
#pragma unroll
        for (int c = 0; c < 2; ++c)
          sacc[ct] = mfma16(kf[ct][c], qf[qs][c], sacc[ct]);
      }
      // scores already in exp2 domain (QSCALE folded into qb)
      float pv[4][4];
      float mx = -1e30f;
#pragma unroll
      for (int ct = 0; ct < 4; ++ct)
#pragma unroll
        for (int r = 0; r < 4; ++r) {
          float s = sacc[ct][r];
          bool ok = (mq >> (ct * 16 + r)) & 1ull;
          s = ok ? s : -1e30f;
          pv[ct][r] = s;
          mx = fmaxf(mx, s);
        }
      mx = fmaxf(mx, __shfl_xor(mx, 16));
      mx = fmaxf(mx, __shfl_xor(mx, 32));       // all lanes: row max for q=lo
      // defer-max: only rescale when some row grew past threshold
      if (__any(mx > mrow[qs] + 11.5f)) {
        float mnew = fmaxf(mrow[qs], mx);
        float fsc = exp2f(mrow[qs] - mnew);     // lane-local (q=lo)
        mrow[qs] = mnew;
        lrow[qs] *= fsc;
#pragma unroll
        for (int od = 0; od < 4; ++od)
          oaccT[qs][od] *= fsc;
      }
      float rs = 0.f;
      char* Pb = (char*)Pl[wave][qs];
#pragma unroll
      for (int ct = 0; ct < 4; ++ct) {
        float p0 = exp2f(pv[ct][0] - mrow[qs]);
        float p1 = exp2f(pv[ct][1] - mrow[qs]);
        float p2 = exp2f(pv[ct][2] - mrow[qs]);
        float p3 = exp2f(pv[ct][3] - mrow[qs]);
        rs += (p0 + p1) + (p2 + p3);
        bf16x4 w = { (bf16)p0, (bf16)p1, (bf16)p2, (bf16)p3 };
        *(bf16x4*)(Pb + lo * 144 + ct * 32 + g * 8) = w;   // b64, 2-way = free
      }
      rs += __shfl_xor(rs, 16);
      rs += __shfl_xor(rs, 32);
      lrow[qs] += rs;
    }

    // PV: O^T = mfma(V-frag, P-frag) -> q stays lane-local
    bf16x8 pf[2][2];
#pragma unroll
    for (int qs = 0; qs < 2; ++qs)
#pragma unroll
      for (int c = 0; c < 2; ++c)
        pf[qs][c] = lds_read8(Pl[wave][qs], lo * 144 + c * 64 + g * 16);
#pragma unroll
    for (int od = 0; od < 4; ++od) {
      bf16x8 vf0 = lds_read8(Vt, swz(od * 16 + lo, 0 * 64 + g * 16));
      bf16x8 vf1 = lds_read8(Vt, swz(od * 16 + lo, 1 * 64 + g * 16));
#pragma unroll
      for (int qs = 0; qs < 2; ++qs) {
        oaccT[qs][od] = mfma16(vf0, pf[qs][0], oaccT[qs][od]);
        oaccT[qs][od] = mfma16(vf1, pf[qs][1], oaccT[qs][od]);
      }
    }
  }

  // epilogue: lane (g,lo) holds O^T[od*16+g*4+r][q=lo] -> f32x4 rows, coalesced
#pragma unroll
  for (int qs = 0; qs < 2; ++qs) {
    float linv = 1.0f / lrow[qs];
    size_t rowb = ((size_t)b * S + q0w + qs * 16 + lo) * D + h * HD;
#pragma unroll
    for (int od = 0; od < 4; ++od) {
      f32x4 o = oaccT[qs][od] * linv;
      *(f32x4*)(ctx + rowb + od * 16 + g * 4) = o;
    }
  }
}

// ---------------- LayerNorms ----------------

DEV void block_stats(float s, float s2, float* red, int tid, float& mu, float& rstd) {
  for (int off = 32; off > 0; off >>= 1) {
    s += __shfl_down(s, off);
    s2 += __shfl_down(s2, off);
  }
  int wave = tid >> 6, lane = tid & 63;
  if (lane == 0) { red[wave] = s; red[4 + wave] = s2; }
  __syncthreads();
  float S1 = red[0] + red[1] + red[2] + red[3];
  float S2 = red[4] + red[5] + red[6] + red[7];
  mu = S1 * (1.f / 1024.f);
  rstd = rsqrtf(S2 * (1.f / 1024.f) - mu * mu + 1e-5f);
}

__global__ __launch_bounds__(256) void ln0_kernel(
    const float* __restrict__ qf, const float* __restrict__ ctx,
    const float* __restrict__ g, const float* __restrict__ beta,
    float* __restrict__ of, bf16* __restrict__ ob)
{
  __shared__ float red[8];
  const int row = blockIdx.x, tid = threadIdx.x;
  const size_t base = (size_t)row * D;
  float4 x = *(const float4*)(qf + base + tid * 4);
  float4 c = *(const float4*)(ctx + base + tid * 4);
  x.x += c.x; x.y += c.y; x.z += c.z; x.w += c.w;
  float mu, rstd;
  block_stats(x.x + x.y + x.z + x.w,
              x.x * x.x + x.y * x.y + x.z * x.z + x.w * x.w, red, tid, mu, rstd);
  float4 gv = *(const float4*)(g + tid * 4);
  float4 bv = *(const float4*)(beta + tid * 4);
  float o0 = (x.x - mu) * rstd * gv.x + bv.x;
  float o1 = (x.y - mu) * rstd * gv.y + bv.y;
  float o2 = (x.z - mu) * rstd * gv.z + bv.z;
  float o3 = (x.w - mu) * rstd * gv.w + bv.w;
  *(float4*)(of + base + tid * 4) = make_float4(o0, o1, o2, o3);
  bf16x4 o = { (bf16)o0, (bf16)o1, (bf16)o2, (bf16)o3 };
  *(bf16x4*)(ob + base + tid * 4) = o;
}

DEV float gelu_exact(float t) { return 0.5f * t * (1.f + erff(t * 0.70710678118654752f)); }

__global__ __launch_bounds__(256) void ln1_kernel(
    const float* __restrict__ of, const float* __restrict__ pf,
    const float* __restrict__ g, const float* __restrict__ beta,
    float* __restrict__ out)
{
  __shared__ float red[8];
  const int row = blockIdx.x, tid = threadIdx.x;
  const size_t base = (size_t)row * D;
  float4 x = *(const float4*)(of + base + tid * 4);
  float4 p = *(const float4*)(pf + base + tid * 4);
  x.x += gelu_exact(p.x); x.y += gelu_exact(p.y);
  x.z += gelu_exact(p.z); x.w += gelu_exact(p.w);
  float mu, rstd;
  block_stats(x.x + x.y + x.z + x.w,
              x.x * x.x + x.y * x.y + x.z * x.z + x.w * x.w, red, tid, mu, rstd);
  float4 gv = *(const float4*)(g + tid * 4);
  float4 bv = *(const float4*)(beta + tid * 4);
  float o0 = (x.x - mu) * rstd * gv.x + bv.x;
  float o1 = (x.y - mu) * rstd * gv.y + bv.y;
  float o2 = (x.z - mu) * rstd * gv.z + bv.z;
  float o3 = (x.w - mu) * rstd * gv.w + bv.w;
  *(float4*)(out + base + tid * 4) = make_float4(o0, o1, o2, o3);
}

// ---------------- launch ----------------

extern "C" void kernel_launch(void* const* d_in, const int* in_sizes, int n_in,
                              void* d_out, int out_size, void* d_ws, size_t ws_size,
                              hipStream_t stream) {
  const float* Q     = (const float*)d_in[0];
  const float* K     = (const float*)d_in[1];
  const int*   mask  = (const int*)d_in[2];
  const float* Wq    = (const float*)d_in[3];
  const float* bq    = (const float*)d_in[4];
  const float* Wk    = (const float*)d_in[5];
  const float* bk    = (const float*)d_in[6];
  const float* Wv    = (const float*)d_in[7];
  const float* bv    = (const float*)d_in[8];
  const float* Wp    = (const float*)d_in[9];
  const float* bp    = (const float*)d_in[10];
  const float* g0    = (const float*)d_in[11];
  const float* beta0 = (const float*)d_in[12];
  const float* g1    = (const float*)d_in[13];
  const float* beta1 = (const float*)d_in[14];
  float* out = (float*)d_out;

  char* w = (char*)d_ws;
  const size_t MB = 1u << 20;
  bf16* Qb  = (bf16*)(w + 0 * MB);
  bf16* Kb  = (bf16*)(w + 16 * MB);
  bf16* Wqt = (bf16*)(w + 32 * MB);
  bf16* Wkt = (bf16*)(w + 34 * MB);
  bf16* Wvt = (bf16*)(w + 36 * MB);
  bf16* Wpt = (bf16*)(w + 38 * MB);
  float* qf = (float*)(w + 40 * MB);
  bf16* qb  = (bf16*)(w + 72 * MB);
  bf16* kb  = (bf16*)(w + 88 * MB);
  bf16* vb  = (bf16*)(w + 104 * MB);
  float* ctx = (float*)(w + 120 * MB);
  float* pf  = ctx;
  float* of  = (float*)(w + 152 * MB);
  bf16* ob   = (bf16*)(w + 0 * MB);   // alias Qb

  dim3 cg(1024, 2);
  cvt_bf16_kernel<<<cg, 256, 0, stream>>>(Q, Qb, K, Kb, M * D);
  dim3 tb(32, 8), tg(32, 32, 4);
  transpose_cvt_kernel<<<tg, tb, 0, stream>>>(Wq, Wqt, Wk, Wkt, Wv, Wvt, Wp, Wpt);

  dim3 gq(8, 64, 3);
  gemm_qkv_kernel<<<gq, 256, 0, stream>>>(Qb, Kb, Wqt, Wkt, Wvt, bq, bk, bv, qf, qb, kb, vb);

  dim3 ag(S / 128, BATCH * H);   // (8, 128)
  attn_kernel<<<ag, 256, 0, stream>>>(qb, kb, vb, mask, ctx);

  ln0_kernel<<<M, 256, 0, stream>>>(qf, ctx, g0, beta0, of, ob);
  dim3 gp(8, 64);
  gemm_p_kernel<<<gp, 256, 0, stream>>>(ob, Wpt, bp, pf);
  ln1_kernel<<<M, 256, 0, stream>>>(of, pf, g1, beta1, out);
}

// Round 6
// 363.232 us; speedup vs baseline: 1.1872x; 1.0499x over previous
//
#include <hip/hip_runtime.h>
#include <hip/hip_bf16.h>
#include <math.h>

#define DEV __device__ __forceinline__

typedef __bf16 bf16;
typedef __bf16 bf16x8 __attribute__((ext_vector_type(8)));
typedef __bf16 bf16x4 __attribute__((ext_vector_type(4)));
typedef __bf16 bf16x2 __attribute__((ext_vector_type(2)));
typedef float f32x4 __attribute__((ext_vector_type(4)));
typedef float f32x16 __attribute__((ext_vector_type(16)));
typedef int i32x2 __attribute__((ext_vector_type(2)));
typedef unsigned int u32;
typedef unsigned long long u64;

static constexpr int BATCH = 8, S = 1024, D = 1024, H = 16, HD = 64;
static constexpr int M = BATCH * S;

// 0.125 (1/sqrt(hd)) * log2(e): folded into qb so softmax runs in exp2 domain
static constexpr float QSCALE = 0.18033688f;

DEV f32x4 mfma16(bf16x8 a, bf16x8 b, f32x4 c) {
  return __builtin_amdgcn_mfma_f32_16x16x32_bf16(a, b, c, 0, 0, 0);
}
DEV f32x16 mfma32(bf16x8 a, bf16x8 b, f32x16 c) {
  return __builtin_amdgcn_mfma_f32_32x32x16_bf16(a, b, c, 0, 0, 0);
}

DEV void gload_lds16(const void* g, void* l) {
  __builtin_amdgcn_global_load_lds(
      (__attribute__((address_space(1))) void*)(g),
      (__attribute__((address_space(3))) void*)(l), 16, 0, 0);
}

DEV bf16x8 lds_read8(const void* base, int byteoff) {
  return *(const bf16x8*)((const char*)base + byteoff);
}

DEV u32 packbf(float a, float b) {
  bf16x2 t = { (bf16)a, (bf16)b };
  return __builtin_bit_cast(u32, t);
}

// ---------------- elementwise converts (fused via grid.y) ----------------

__global__ void cvt_bf16_kernel(const float* __restrict__ in0, bf16* __restrict__ out0,
                                const float* __restrict__ in1, bf16* __restrict__ out1, int n) {
  const float* in = blockIdx.y ? in1 : in0;
  bf16* out = blockIdx.y ? out1 : out0;
  int i = (blockIdx.x * blockDim.x + threadIdx.x) * 4;
  int stride = gridDim.x * blockDim.x * 4;
  for (; i < n; i += stride) {
    float4 v = *(const float4*)(in + i);
    bf16x4 o = { (bf16)v.x, (bf16)v.y, (bf16)v.z, (bf16)v.w };
    *(bf16x4*)(out + i) = o;
  }
}

// W [K][N] f32 -> Wt [N][K] bf16; z selects which weight
__global__ void transpose_cvt_kernel(const float* __restrict__ w0, bf16* __restrict__ o0,
                                     const float* __restrict__ w1, bf16* __restrict__ o1,
                                     const float* __restrict__ w2, bf16* __restrict__ o2,
                                     const float* __restrict__ w3, bf16* __restrict__ o3) {
  const int z = blockIdx.z;
  const float* in = z == 0 ? w0 : z == 1 ? w1 : z == 2 ? w2 : w3;
  bf16* out = z == 0 ? o0 : z == 1 ? o1 : z == 2 ? o2 : o3;
  __shared__ float t[32][33];
  int n0 = blockIdx.x * 32, k0 = blockIdx.y * 32;
  int tx = threadIdx.x, ty = threadIdx.y;   // block (32,8)
  for (int i = 0; i < 32; i += 8)
    t[ty + i][tx] = in[(size_t)(k0 + ty + i) * D + n0 + tx];
  __syncthreads();
  for (int i = 0; i < 32; i += 8)
    out[(size_t)(n0 + ty + i) * D + k0 + tx] = (bf16)t[tx][ty + i];
}

// ---------------- GEMM body (m97 structure) ----------------

template<int MODE>  // 0: f32 + scaled bf16 (q), 1: bf16 only, 2: f32 only
DEV void gemm_body(const bf16* A, const bf16* Bt, const float* bias,
                   float* Cf, bf16* Cb, float osc,
                   bf16* As, bf16* Bs) {
  constexpr int K = 1024, N = 1024, BK = 32;
  const int tid = threadIdx.x, lane = tid & 63, wave = tid >> 6;
  int f = blockIdx.y * 8 + blockIdx.x;          // gridDim (8,64) -> 512
  f = (f & 7) * 64 + (f >> 3);                  // XCD-chunked, bijective
  const int bm = f >> 3, bn = f & 7;
  const int wr = wave >> 1, wc = wave & 1;
  f32x4 acc[4][4] = {};
  const char* Ab = (const char*)(A + (size_t)bm * 128 * K);
  const char* Bb = (const char*)(Bt + (size_t)bn * 128 * K);

  for (int kt = 0; kt < K / BK; ++kt) {
    __syncthreads();
    const int k0b = kt * (BK * 2);
    for (int i = 0; i < 2; ++i) {
      int cbase = (wave * 2 + i) * 1024;
      int off = cbase + lane * 16;
      int row = off >> 6, col = off & 63;
      gload_lds16(Ab + (size_t)row * (K * 2) + k0b + col, (char*)As + cbase);
      gload_lds16(Bb + (size_t)row * (K * 2) + k0b + col, (char*)Bs + cbase);
    }
    __syncthreads();
    bf16x8 af[4], bfr[4];
    for (int mi = 0; mi < 4; ++mi)
      af[mi] = lds_read8(As, (wr * 64 + mi * 16 + (lane & 15)) * 64 + (lane >> 4) * 16);
    for (int ni = 0; ni < 4; ++ni)
      bfr[ni] = lds_read8(Bs, (wc * 64 + ni * 16 + (lane & 15)) * 64 + (lane >> 4) * 16);
    for (int mi = 0; mi < 4; ++mi)
      for (int ni = 0; ni < 4; ++ni)
        acc[mi][ni] = mfma16(af[mi], bfr[ni], acc[mi][ni]);
  }

  const int rbase = bm * 128 + wr * 64;
  const int cbase = bn * 128 + wc * 64;
  for (int ni = 0; ni < 4; ++ni) {
    int col = cbase + ni * 16 + (lane & 15);
    float bv = bias[col];
    for (int mi = 0; mi < 4; ++mi) {
      int row0 = rbase + mi * 16 + (lane >> 4) * 4;
      for (int r = 0; r < 4; ++r) {
        float v = acc[mi][ni][r] + bv;
        size_t idx = (size_t)(row0 + r) * N + col;
        if (MODE == 0) { Cf[idx] = v; Cb[idx] = (bf16)(v * osc); }
        if (MODE == 1) { Cb[idx] = (bf16)v; }
        if (MODE == 2) { Cf[idx] = v; }
      }
    }
  }
}

__global__ __launch_bounds__(256) void gemm_qkv_kernel(
    const bf16* __restrict__ Qb, const bf16* __restrict__ Kb,
    const bf16* __restrict__ Wqt, const bf16* __restrict__ Wkt, const bf16* __restrict__ Wvt,
    const float* __restrict__ bq, const float* __restrict__ bk, const float* __restrict__ bv,
    float* __restrict__ qf, bf16* __restrict__ qb,
    bf16* __restrict__ kb, bf16* __restrict__ vb)
{
  __shared__ bf16 As[128 * 32];
  __shared__ bf16 Bs[128 * 32];
  const int z = blockIdx.z;
  if (z == 0)      gemm_body<0>(Qb, Wqt, bq, qf, qb, QSCALE, As, Bs);
  else if (z == 1) gemm_body<1>(Kb, Wkt, bk, nullptr, kb, 1.f, As, Bs);
  else             gemm_body<1>(Kb, Wvt, bv, nullptr, vb, 1.f, As, Bs);
}

__global__ __launch_bounds__(256) void gemm_p_kernel(
    const bf16* __restrict__ A, const bf16* __restrict__ Bt,
    const float* __restrict__ bias, float* __restrict__ Cf)
{
  __shared__ bf16 As[128 * 32];
  __shared__ bf16 Bs[128 * 32];
  gemm_body<2>(A, Bt, bias, Cf, nullptr, 1.f, As, Bs);
}

// ---------------- flash attention, 32x32 MFMA, no P-LDS ----------------
// Swapped QK^T: S^T[kv][q] = mfma32(K-frag, Q-frag), q = lane&31 (lane-local
// softmax). PV: O^T[hd][q] = mfma32(Vt-frag, P-frag); P-frag built in-register
// from packed bf16 words via ONE permlane32_swap per word pair (no LDS).
// permlane32_swap(vdst,src): new_vdst[32:63]=old_src[0:31],
// new_src[0:31]=old_vdst[32:63]; ret = {new_vdst, new_src}.
// Call with vdst = LOW-rr word (X=W[sub][2tt]), src = HIGH-rr word
// (Y=W[sub][2tt+1]):
//   ret[0] = {X(half0)|Y(half0)} = frag word j0..3 for both lane-halves
//   ret[1] = {X(half1)|Y(half1)} = frag word j4..7 for both lane-halves

DEV int swz(int row, int colb) { return row * 128 + (colb ^ ((row & 7) << 4)); }

__global__ __launch_bounds__(256, 3) void attn_kernel(
    const bf16* __restrict__ q, const bf16* __restrict__ k, const bf16* __restrict__ v,
    const int* __restrict__ mask, float* __restrict__ ctx)
{
  __shared__ bf16 Kl[2][64 * 64];   // [kv][hd] swizzled
  __shared__ bf16 Vt[2][64 * 64];   // [hd][kv] swizzled
  const int tid = threadIdx.x, lane = tid & 63, wave = tid >> 6;
  const int hi = lane >> 5, lq = lane & 31;
  // XCD-aware remap: all 8 q-tiles of one (b,h) land on one XCD (shared K/V in L2)
  const int wg = blockIdx.x;
  const int xcd = wg & 7, ix = wg >> 3;
  const int bh = xcd * 16 + (ix & 15);
  const int qt = ix >> 4;                 // 0..7
  const int b = bh >> 4, h = bh & 15;
  const int q0 = qt * 128 + wave * 32;
  const size_t base = (size_t)b * S * D + (size_t)h * HD;

  // Q fragments (B-operand): k_dim = hc*16 + hi*8 + j, col q = lq
  bf16x8 qf[4];
#pragma unroll
  for (int hc = 0; hc < 4; ++hc)
    qf[hc] = *(const bf16x8*)(q + base + (size_t)(q0 + lq) * D + hc * 16 + hi * 8);

  f32x16 oaccT[2] = {};     // O^T[hd = (reg&3)+8*(reg>>2)+4*hi+32*hdsub][q=lq]
  float mrow = -3e38f, lrow = 0.f;

  // staging registers
  bf16x8 kst[2], vst[2];
  const int koff = tid * 16;              // k-stage: rows of 128B
  const int krow = koff >> 7, kcol = koff & 127;

#define LOADK(KV0)                                                              \
  {                                                                             \
    _Pragma("unroll")                                                           \
    for (int rr = 0; rr < 2; ++rr)                                              \
      kst[rr] = *(const bf16x8*)((const char*)(k + base +                       \
                 (size_t)((KV0) + rr * 32 + krow) * D) + kcol);                 \
    _Pragma("unroll")                                                           \
    for (int rr = 0; rr < 2; ++rr) {                                            \
      int kvr = rr * 32 + wave * 8;                                             \
      _Pragma("unroll")                                                         \
      for (int i = 0; i < 8; ++i)                                               \
        vst[rr][i] = v[base + (size_t)((KV0) + kvr + i) * D + lane];            \
    }                                                                           \
  }

#define WRITEK(BI)                                                              \
  {                                                                             \
    _Pragma("unroll")                                                           \
    for (int rr = 0; rr < 2; ++rr)                                              \
      *(bf16x8*)((char*)Kl[BI] + swz(rr * 32 + krow, kcol)) = kst[rr];          \
    _Pragma("unroll")                                                           \
    for (int rr = 0; rr < 2; ++rr)                                              \
      *(bf16x8*)((char*)Vt[BI] + swz(lane, (rr * 32 + wave * 8) * 2)) = vst[rr];\
  }

  LOADK(0);
  WRITEK(0);

  for (int kt = 0; kt < S / 64; ++kt) {
    const int cur = kt & 1;
    const int kv0 = kt * 64;
    __syncthreads();                       // buf[cur] staged, buf[cur^1] free
    if (kt < S / 64 - 1) LOADK(kv0 + 64);  // issue next-tile globals early

    const char* Kb_ = (const char*)Kl[cur];
    const char* Vb_ = (const char*)Vt[cur];

    u64 mv = __ballot(mask[b * S + kv0 + lane] != 0);

    // QK^T: S^T[kv 64][q 32] in 2 kv-subtiles
    f32x16 sacc[2];
    __builtin_amdgcn_s_setprio(1);
#pragma unroll
    for (int sub = 0; sub < 2; ++sub) {
      f32x16 a = {};
#pragma unroll
      for (int hc = 0; hc < 4; ++hc) {
        bf16x8 kf = lds_read8(Kb_, swz(sub * 32 + lq, hc * 32 + hi * 16));
        a = mfma32(kf, qf[hc], a);
      }
      sacc[sub] = a;
    }
    __builtin_amdgcn_s_setprio(0);

    // mask (fast path: fully valid tile) + row max (q = lq, partner l^32)
    float mx = -3e38f;
    if (mv == ~0ull) {
#pragma unroll
      for (int sub = 0; sub < 2; ++sub)
#pragma unroll
        for (int r = 0; r < 16; ++r) mx = fmaxf(mx, sacc[sub][r]);
    } else {
      u64 mqh = mv >> (hi * 4);
#pragma unroll
      for (int sub = 0; sub < 2; ++sub)
#pragma unroll
        for (int rr = 0; rr < 4; ++rr)
#pragma unroll
          for (int rm = 0; rm < 4; ++rm) {
            int reg = rr * 4 + rm;
            bool ok = (mqh >> (rm + 8 * rr + 32 * sub)) & 1ull;
            float s = ok ? sacc[sub][reg] : -1e30f;
            sacc[sub][reg] = s;
            mx = fmaxf(mx, s);
          }
    }
    mx = fmaxf(mx, __shfl_xor(mx, 32));

    // defer-max: rescale only when row max grew past threshold (exp2 domain)
    if (__any(mx > mrow + 11.5f)) {
      float mnew = fmaxf(mrow, mx);
      float fsc = exp2f(mrow - mnew);
      mrow = mnew;
      lrow *= fsc;
      oaccT[0] *= fsc;
      oaccT[1] *= fsc;
    }

    // P = exp2(S - m), packed to bf16 words; row-sum
    float rs = 0.f;
    u32 W[2][4][2];
#pragma unroll
    for (int sub = 0; sub < 2; ++sub)
#pragma unroll
      for (int rr = 0; rr < 4; ++rr)
#pragma unroll
        for (int hh = 0; hh < 2; ++hh) {
          float p0 = exp2f(sacc[sub][rr * 4 + 2 * hh] - mrow);
          float p1 = exp2f(sacc[sub][rr * 4 + 2 * hh + 1] - mrow);
          rs += p0 + p1;
          W[sub][rr][hh] = packbf(p0, p1);
        }
    rs += __shfl_xor(rs, 32);
    lrow += rs;

    // P-frags: frag t needs kv = 16t + 8*hi + j.
    bf16x8 pfr[4];
#pragma unroll
    for (int t = 0; t < 4; ++t) {
      const int sub = t >> 1, r0 = 2 * (t & 1);
      i32x2 s0 = __builtin_amdgcn_permlane32_swap(
          (int)W[sub][r0][0], (int)W[sub][r0 + 1][0], false, false);
      i32x2 s1 = __builtin_amdgcn_permlane32_swap(
          (int)W[sub][r0][1], (int)W[sub][r0 + 1][1], false, false);
      u32 wd[4] = { (u32)s0[0], (u32)s1[0], (u32)s0[1], (u32)s1[1] };
      pfr[t] = __builtin_bit_cast(bf16x8, wd);
    }

    // PV: O^T[hd][q] += Vt-frag x P-frag
    __builtin_amdgcn_s_setprio(1);
#pragma unroll
    for (int hdsub = 0; hdsub < 2; ++hdsub) {
      f32x16 a = oaccT[hdsub];
#pragma unroll
      for (int t = 0; t < 4; ++t) {
        bf16x8 vf = lds_read8(Vb_, swz(hdsub * 32 + lq, t * 32 + hi * 16));
        a = mfma32(vf, pfr[t], a);
      }
      oaccT[hdsub] = a;
    }
    __builtin_amdgcn_s_setprio(0);

    if (kt < S / 64 - 1) WRITEK(cur ^ 1);  // stage next tile (after compute)
  }

  // epilogue: lane holds O^T[hd = rm+8rr+4hi+32hdsub][q=lq] -> f32x4 stores
  float linv = 1.0f / lrow;
  size_t rowb = ((size_t)b * S + q0 + lq) * D + (size_t)h * HD;
#pragma unroll
  for (int hdsub = 0; hdsub < 2; ++hdsub)
#pragma unroll
    for (int rr = 0; rr < 4; ++rr) {
      f32x4 o = { oaccT[hdsub][rr * 4 + 0] * linv, oaccT[hdsub][rr * 4 + 1] * linv,
                  oaccT[hdsub][rr * 4 + 2] * linv, oaccT[hdsub][rr * 4 + 3] * linv };
      *(f32x4*)(ctx + rowb + 32 * hdsub + 8 * rr + 4 * hi) = o;
    }
}

// ---------------- LayerNorms ----------------

DEV void block_stats(float s, float s2, float* red, int tid, float& mu, float& rstd) {
  for (int off = 32; off > 0; off >>= 1) {
    s += __shfl_down(s, off);
    s2 += __shfl_down(s2, off);
  }
  int wave = tid >> 6, lane = tid & 63;
  if (lane == 0) { red[wave] = s; red[4 + wave] = s2; }
  __syncthreads();
  float S1 = red[0] + red[1] + red[2] + red[3];
  float S2 = red[4] + red[5] + red[6] + red[7];
  mu = S1 * (1.f / 1024.f);
  rstd = rsqrtf(S2 * (1.f / 1024.f) - mu * mu + 1e-5f);
}

__global__ __launch_bounds__(256) void ln0_kernel(
    const float* __restrict__ qf, const float* __restrict__ ctx,
    const float* __restrict__ g, const float* __restrict__ beta,
    float* __restrict__ of, bf16* __restrict__ ob)
{
  __shared__ float red[8];
  const int row = blockIdx.x, tid = threadIdx.x;
  const size_t base = (size_t)row * D;
  float4 x = *(const float4*)(qf + base + tid * 4);
  float4 c = *(const float4*)(ctx + base + tid * 4);
  x.x += c.x; x.y += c.y; x.z += c.z; x.w += c.w;
  float mu, rstd;
  block_stats(x.x + x.y + x.z + x.w,
              x.x * x.x + x.y * x.y + x.z * x.z + x.w * x.w, red, tid, mu, rstd);
  float4 gv = *(const float4*)(g + tid * 4);
  float4 bv = *(const float4*)(beta + tid * 4);
  float o0 = (x.x - mu) * rstd * gv.x + bv.x;
  float o1 = (x.y - mu) * rstd * gv.y + bv.y;
  float o2 = (x.z - mu) * rstd * gv.z + bv.z;
  float o3 = (x.w - mu) * rstd * gv.w + bv.w;
  *(float4*)(of + base + tid * 4) = make_float4(o0, o1, o2, o3);
  bf16x4 o = { (bf16)o0, (bf16)o1, (bf16)o2, (bf16)o3 };
  *(bf16x4*)(ob + base + tid * 4) = o;
}

DEV float gelu_exact(float t) { return 0.5f * t * (1.f + erff(t * 0.70710678118654752f)); }

__global__ __launch_bounds__(256) void ln1_kernel(
    const float* __restrict__ of, const float* __restrict__ pf,
    const float* __restrict__ g, const float* __restrict__ beta,
    float* __restrict__ out)
{
  __shared__ float red[8];
  const int row = blockIdx.x, tid = threadIdx.x;
  const size_t base = (size_t)row * D;
  float4 x = *(const float4*)(of + base + tid * 4);
  float4 p = *(const float4*)(pf + base + tid * 4);
  x.x += gelu_exact(p.x); x.y += gelu_exact(p.y);
  x.z += gelu_exact(p.z); x.w += gelu_exact(p.w);
  float mu, rstd;
  block_stats(x.x + x.y + x.z + x.w,
              x.x * x.x + x.y * x.y + x.z * x.z + x.w * x.w, red, tid, mu, rstd);
  float4 gv = *(const float4*)(g + tid * 4);
  float4 bv = *(const float4*)(beta + tid * 4);
  float o0 = (x.x - mu) * rstd * gv.x + bv.x;
  float o1 = (x.y - mu) * rstd * gv.y + bv.y;
  float o2 = (x.z - mu) * rstd * gv.z + bv.z;
  float o3 = (x.w - mu) * rstd * gv.w + bv.w;
  *(float4*)(out + base + tid * 4) = make_float4(o0, o1, o2, o3);
}

// ---------------- launch ----------------

extern "C" void kernel_launch(void* const* d_in, const int* in_sizes, int n_in,
                              void* d_out, int out_size, void* d_ws, size_t ws_size,
                              hipStream_t stream) {
  const float* Q     = (const float*)d_in[0];
  const float* K     = (const float*)d_in[1];
  const int*   mask  = (const int*)d_in[2];
  const float* Wq    = (const float*)d_in[3];
  const float* bq    = (const float*)d_in[4];
  const float* Wk    = (const float*)d_in[5];
  const float* bk    = (const float*)d_in[6];
  const float* Wv    = (const float*)d_in[7];
  const float* bv    = (const float*)d_in[8];
  const float* Wp    = (const float*)d_in[9];
  const float* bp    = (const float*)d_in[10];
  const float* g0    = (const float*)d_in[11];
  const float* beta0 = (const float*)d_in[12];
  const float* g1    = (const float*)d_in[13];
  const float* beta1 = (const float*)d_in[14];
  float* out = (float*)d_out;

  char* w = (char*)d_ws;
  const size_t MB = 1u << 20;
  bf16* Qb  = (bf16*)(w + 0 * MB);
  bf16* Kb  = (bf16*)(w + 16 * MB);
  bf16* Wqt = (bf16*)(w + 32 * MB);
  bf16* Wkt = (bf16*)(w + 34 * MB);
  bf16* Wvt = (bf16*)(w + 36 * MB);
  bf16* Wpt = (bf16*)(w + 38 * MB);
  float* qf = (float*)(w + 40 * MB);
  bf16* qb  = (bf16*)(w + 72 * MB);
  bf16* kb  = (bf16*)(w + 88 * MB);
  bf16* vb  = (bf16*)(w + 104 * MB);
  float* ctx = (float*)(w + 120 * MB);
  float* pf  = ctx;
  float* of  = (float*)(w + 152 * MB);
  bf16* ob   = (bf16*)(w + 0 * MB);   // alias Qb

  dim3 cg(1024, 2);
  cvt_bf16_kernel<<<cg, 256, 0, stream>>>(Q, Qb, K, Kb, M * D);
  dim3 tb(32, 8), tg(32, 32, 4);
  transpose_cvt_kernel<<<tg, tb, 0, stream>>>(Wq, Wqt, Wk, Wkt, Wv, Wvt, Wp, Wpt);

  dim3 gq(8, 64, 3);
  gemm_qkv_kernel<<<gq, 256, 0, stream>>>(Qb, Kb, Wqt, Wkt, Wvt, bq, bk, bv, qf, qb, kb, vb);

  attn_kernel<<<1024, 256, 0, stream>>>(qb, kb, vb, mask, ctx);

  ln0_kernel<<<M, 256, 0, stream>>>(qf, ctx, g0, beta0, of, ob);
  dim3 gp(8, 64);
  gemm_p_kernel<<<gp, 256, 0, stream>>>(ob, Wpt, bp, pf);
  ln1_kernel<<<M, 256, 0, stream>>>(of, pf, g1, beta1, out);
}

// Round 9
// 340.721 us; speedup vs baseline: 1.2656x; 1.0661x over previous
//
#include <hip/hip_runtime.h>
#include <hip/hip_bf16.h>
#include <math.h>

#define DEV __device__ __forceinline__

typedef __bf16 bf16;
typedef __bf16 bf16x8 __attribute__((ext_vector_type(8)));
typedef __bf16 bf16x4 __attribute__((ext_vector_type(4)));
typedef __bf16 bf16x2 __attribute__((ext_vector_type(2)));
typedef float f32x4 __attribute__((ext_vector_type(4)));
typedef float f32x16 __attribute__((ext_vector_type(16)));
typedef int i32x2 __attribute__((ext_vector_type(2)));
typedef unsigned int u32;
typedef unsigned long long u64;

static constexpr int BATCH = 8, S = 1024, D = 1024, H = 16, HD = 64;
static constexpr int M = BATCH * S;

// 0.125 (1/sqrt(hd)) * log2(e): folded into qb so softmax runs in exp2 domain
static constexpr float QSCALE = 0.18033688f;
static constexpr float INVQSCALE = 5.54517744f;   // 1/QSCALE

DEV f32x4 mfma16(bf16x8 a, bf16x8 b, f32x4 c) {
  return __builtin_amdgcn_mfma_f32_16x16x32_bf16(a, b, c, 0, 0, 0);
}
DEV f32x16 mfma32(bf16x8 a, bf16x8 b, f32x16 c) {
  return __builtin_amdgcn_mfma_f32_32x32x16_bf16(a, b, c, 0, 0, 0);
}

DEV void gload_lds16(const void* g, void* l) {
  __builtin_amdgcn_global_load_lds(
      (__attribute__((address_space(1))) void*)(g),
      (__attribute__((address_space(3))) void*)(l), 16, 0, 0);
}

DEV bf16x8 lds_read8(const void* base, int byteoff) {
  return *(const bf16x8*)((const char*)base + byteoff);
}

DEV u32 packbf(float a, float b) {
  bf16x2 t = { (bf16)a, (bf16)b };
  return __builtin_bit_cast(u32, t);
}

// ---------------- elementwise converts (fused via grid.y) ----------------

__global__ void cvt_bf16_kernel(const float* __restrict__ in0, bf16* __restrict__ out0,
                                const float* __restrict__ in1, bf16* __restrict__ out1, int n) {
  const float* in = blockIdx.y ? in1 : in0;
  bf16* out = blockIdx.y ? out1 : out0;
  int i = (blockIdx.x * blockDim.x + threadIdx.x) * 4;
  int stride = gridDim.x * blockDim.x * 4;
  for (; i < n; i += stride) {
    float4 v = *(const float4*)(in + i);
    bf16x4 o = { (bf16)v.x, (bf16)v.y, (bf16)v.z, (bf16)v.w };
    *(bf16x4*)(out + i) = o;
  }
}

// W [K][N] f32 -> Wt [N][K] bf16; z selects which weight
__global__ void transpose_cvt_kernel(const float* __restrict__ w0, bf16* __restrict__ o0,
                                     const float* __restrict__ w1, bf16* __restrict__ o1,
                                     const float* __restrict__ w2, bf16* __restrict__ o2,
                                     const float* __restrict__ w3, bf16* __restrict__ o3) {
  const int z = blockIdx.z;
  const float* in = z == 0 ? w0 : z == 1 ? w1 : z == 2 ? w2 : w3;
  bf16* out = z == 0 ? o0 : z == 1 ? o1 : z == 2 ? o2 : o3;
  __shared__ float t[32][33];
  int n0 = blockIdx.x * 32, k0 = blockIdx.y * 32;
  int tx = threadIdx.x, ty = threadIdx.y;   // block (32,8)
  for (int i = 0; i < 32; i += 8)
    t[ty + i][tx] = in[(size_t)(k0 + ty + i) * D + n0 + tx];
  __syncthreads();
  for (int i = 0; i < 32; i += 8)
    out[(size_t)(n0 + ty + i) * D + k0 + tx] = (bf16)t[tx][ty + i];
}

// ---------------- GEMM body (m97 structure + XOR-swizzled LDS) ----------------
// LDS tile [128][32] bf16 (64B rows). Logical (row, slot g of 16B) lives at
// physical slot g ^ (row&3): staging pre-swizzles the GLOBAL source col
// (global_load_lds dest must stay linear, rule #21), fragment read applies the
// same involution. 8-lane b128 phase -> 2-way banks (free) instead of 4-way.

DEV void gemm_body(const bf16* A, const bf16* Bt, const float* bias,
                   bf16* Cb, float osc, bf16* As, bf16* Bs) {
  constexpr int K = 1024, N = 1024, BK = 32;
  const int tid = threadIdx.x, lane = tid & 63, wave = tid >> 6;
  const int lo = lane & 15, g = lane >> 4;
  int f = blockIdx.y * 8 + blockIdx.x;          // gridDim (8,64) -> 512
  f = (f & 7) * 64 + (f >> 3);                  // XCD-chunked, bijective
  const int bm = f >> 3, bn = f & 7;
  const int wr = wave >> 1, wc = wave & 1;
  f32x4 acc[4][4] = {};
  const char* Ab = (const char*)(A + (size_t)bm * 128 * K);
  const char* Bb = (const char*)(Bt + (size_t)bn * 128 * K);

  // staging geometry (swizzled source)
  const int srow[2] = { (wave * 2 + 0) * 16 + (lane >> 2), (wave * 2 + 1) * 16 + (lane >> 2) };
  const int sslot = lane & 3;

  for (int kt = 0; kt < K / BK; ++kt) {
    __syncthreads();
    const int k0b = kt * (BK * 2);
    for (int i = 0; i < 2; ++i) {
      int cbase = (wave * 2 + i) * 1024;
      int row = srow[i];
      int scol = ((sslot ^ (row & 3)) << 4);
      gload_lds16(Ab + (size_t)row * (K * 2) + k0b + scol, (char*)As + cbase);
      gload_lds16(Bb + (size_t)row * (K * 2) + k0b + scol, (char*)Bs + cbase);
    }
    __syncthreads();
    bf16x8 af[4], bfr[4];
    for (int mi = 0; mi < 4; ++mi) {
      int ar = wr * 64 + mi * 16 + lo;
      af[mi] = lds_read8(As, ar * 64 + ((g ^ (ar & 3)) << 4));
    }
    for (int ni = 0; ni < 4; ++ni) {
      int br = wc * 64 + ni * 16 + lo;
      bfr[ni] = lds_read8(Bs, br * 64 + ((g ^ (br & 3)) << 4));
    }
    for (int mi = 0; mi < 4; ++mi)
      for (int ni = 0; ni < 4; ++ni)
        acc[mi][ni] = mfma16(af[mi], bfr[ni], acc[mi][ni]);
  }

  const int rbase = bm * 128 + wr * 64;
  const int cbase = bn * 128 + wc * 64;
  for (int ni = 0; ni < 4; ++ni) {
    int col = cbase + ni * 16 + lo;
    float bv = bias[col];
    for (int mi = 0; mi < 4; ++mi) {
      int row0 = rbase + mi * 16 + g * 4;
      for (int r = 0; r < 4; ++r) {
        float v = acc[mi][ni][r] + bv;
        Cb[(size_t)(row0 + r) * N + col] = (bf16)(v * osc);
      }
    }
  }
}

__global__ __launch_bounds__(256) void gemm_qkv_kernel(
    const bf16* __restrict__ Qb, const bf16* __restrict__ Kb,
    const bf16* __restrict__ Wqt, const bf16* __restrict__ Wkt, const bf16* __restrict__ Wvt,
    const float* __restrict__ bq, const float* __restrict__ bk, const float* __restrict__ bv,
    bf16* __restrict__ qb, bf16* __restrict__ kb, bf16* __restrict__ vb)
{
  __shared__ bf16 As[128 * 32];
  __shared__ bf16 Bs[128 * 32];
  const int z = blockIdx.z;
  if (z == 0)      gemm_body(Qb, Wqt, bq, qb, QSCALE, As, Bs);
  else if (z == 1) gemm_body(Kb, Wkt, bk, kb, 1.f, As, Bs);
  else             gemm_body(Kb, Wvt, bv, vb, 1.f, As, Bs);
}

__global__ __launch_bounds__(256) void gemm_p_kernel(
    const bf16* __restrict__ A, const bf16* __restrict__ Bt,
    const float* __restrict__ bias, bf16* __restrict__ Cb)
{
  __shared__ bf16 As[128 * 32];
  __shared__ bf16 Bs[128 * 32];
  gemm_body(A, Bt, bias, Cb, 1.f, As, Bs);
}

// ---------------- flash attention, 32x32 MFMA, no P-LDS (unchanged) ----------

DEV int swz(int row, int colb) { return row * 128 + (colb ^ ((row & 7) << 4)); }

__global__ __launch_bounds__(256, 3) void attn_kernel(
    const bf16* __restrict__ q, const bf16* __restrict__ k, const bf16* __restrict__ v,
    const int* __restrict__ mask, float* __restrict__ ctx)
{
  __shared__ bf16 Kl[2][64 * 64];   // [kv][hd] swizzled
  __shared__ bf16 Vt[2][64 * 64];   // [hd][kv] swizzled
  const int tid = threadIdx.x, lane = tid & 63, wave = tid >> 6;
  const int hi = lane >> 5, lq = lane & 31;
  const int wg = blockIdx.x;
  const int xcd = wg & 7, ix = wg >> 3;
  const int bh = xcd * 16 + (ix & 15);
  const int qt = ix >> 4;                 // 0..7
  const int b = bh >> 4, h = bh & 15;
  const int q0 = qt * 128 + wave * 32;
  const size_t base = (size_t)b * S * D + (size_t)h * HD;

  bf16x8 qf[4];
#pragma unroll
  for (int hc = 0; hc < 4; ++hc)
    qf[hc] = *(const bf16x8*)(q + base + (size_t)(q0 + lq) * D + hc * 16 + hi * 8);

  f32x16 oaccT[2] = {};     // O^T[hd = (reg&3)+8*(reg>>2)+4*hi+32*hdsub][q=lq]
  float mrow = -3e38f, lrow = 0.f;

  bf16x8 kst[2], vst[2];
  const int koff = tid * 16;              // k-stage: rows of 128B
  const int krow = koff >> 7, kcol = koff & 127;

#define LOADK(KV0)                                                              \
  {                                                                             \
    _Pragma("unroll")                                                           \
    for (int rr = 0; rr < 2; ++rr)                                              \
      kst[rr] = *(const bf16x8*)((const char*)(k + base +                       \
                 (size_t)((KV0) + rr * 32 + krow) * D) + kcol);                 \
    _Pragma("unroll")                                                           \
    for (int rr = 0; rr < 2; ++rr) {                                            \
      int kvr = rr * 32 + wave * 8;                                             \
      _Pragma("unroll")                                                         \
      for (int i = 0; i < 8; ++i)                                               \
        vst[rr][i] = v[base + (size_t)((KV0) + kvr + i) * D + lane];            \
    }                                                                           \
  }

#define WRITEK(BI)                                                              \
  {                                                                             \
    _Pragma("unroll")                                                           \
    for (int rr = 0; rr < 2; ++rr)                                              \
      *(bf16x8*)((char*)Kl[BI] + swz(rr * 32 + krow, kcol)) = kst[rr];          \
    _Pragma("unroll")                                                           \
    for (int rr = 0; rr < 2; ++rr)                                              \
      *(bf16x8*)((char*)Vt[BI] + swz(lane, (rr * 32 + wave * 8) * 2)) = vst[rr];\
  }

  LOADK(0);
  WRITEK(0);

  for (int kt = 0; kt < S / 64; ++kt) {
    const int cur = kt & 1;
    const int kv0 = kt * 64;
    __syncthreads();                       // buf[cur] staged, buf[cur^1] free
    if (kt < S / 64 - 1) LOADK(kv0 + 64);  // issue next-tile globals early

    const char* Kb_ = (const char*)Kl[cur];
    const char* Vb_ = (const char*)Vt[cur];

    u64 mv = __ballot(mask[b * S + kv0 + lane] != 0);

    f32x16 sacc[2];
    __builtin_amdgcn_s_setprio(1);
#pragma unroll
    for (int sub = 0; sub < 2; ++sub) {
      f32x16 a = {};
#pragma unroll
      for (int hc = 0; hc < 4; ++hc) {
        bf16x8 kf = lds_read8(Kb_, swz(sub * 32 + lq, hc * 32 + hi * 16));
        a = mfma32(kf, qf[hc], a);
      }
      sacc[sub] = a;
    }
    __builtin_amdgcn_s_setprio(0);

    float mx = -3e38f;
    if (mv == ~0ull) {
#pragma unroll
      for (int sub = 0; sub < 2; ++sub)
#pragma unroll
        for (int r = 0; r < 16; ++r) mx = fmaxf(mx, sacc[sub][r]);
    } else {
      u64 mqh = mv >> (hi * 4);
#pragma unroll
      for (int sub = 0; sub < 2; ++sub)
#pragma unroll
        for (int rr = 0; rr < 4; ++rr)
#pragma unroll
          for (int rm = 0; rm < 4; ++rm) {
            int reg = rr * 4 + rm;
            bool ok = (mqh >> (rm + 8 * rr + 32 * sub)) & 1ull;
            float s = ok ? sacc[sub][reg] : -1e30f;
            sacc[sub][reg] = s;
            mx = fmaxf(mx, s);
          }
    }
    mx = fmaxf(mx, __shfl_xor(mx, 32));

    if (__any(mx > mrow + 11.5f)) {
      float mnew = fmaxf(mrow, mx);
      float fsc = exp2f(mrow - mnew);
      mrow = mnew;
      lrow *= fsc;
      oaccT[0] *= fsc;
      oaccT[1] *= fsc;
    }

    float rs = 0.f;
    u32 W[2][4][2];
#pragma unroll
    for (int sub = 0; sub < 2; ++sub)
#pragma unroll
      for (int rr = 0; rr < 4; ++rr)
#pragma unroll
        for (int hh = 0; hh < 2; ++hh) {
          float p0 = exp2f(sacc[sub][rr * 4 + 2 * hh] - mrow);
          float p1 = exp2f(sacc[sub][rr * 4 + 2 * hh + 1] - mrow);
          rs += p0 + p1;
          W[sub][rr][hh] = packbf(p0, p1);
        }
    rs += __shfl_xor(rs, 32);
    lrow += rs;

    bf16x8 pfr[4];
#pragma unroll
    for (int t = 0; t < 4; ++t) {
      const int sub = t >> 1, r0 = 2 * (t & 1);
      i32x2 s0 = __builtin_amdgcn_permlane32_swap(
          (int)W[sub][r0][0], (int)W[sub][r0 + 1][0], false, false);
      i32x2 s1 = __builtin_amdgcn_permlane32_swap(
          (int)W[sub][r0][1], (int)W[sub][r0 + 1][1], false, false);
      u32 wd[4] = { (u32)s0[0], (u32)s1[0], (u32)s0[1], (u32)s1[1] };
      pfr[t] = __builtin_bit_cast(bf16x8, wd);
    }

    __builtin_amdgcn_s_setprio(1);
#pragma unroll
    for (int hdsub = 0; hdsub < 2; ++hdsub) {
      f32x16 a = oaccT[hdsub];
#pragma unroll
      for (int t = 0; t < 4; ++t) {
        bf16x8 vf = lds_read8(Vb_, swz(hdsub * 32 + lq, t * 32 + hi * 16));
        a = mfma32(vf, pfr[t], a);
      }
      oaccT[hdsub] = a;
    }
    __builtin_amdgcn_s_setprio(0);

    if (kt < S / 64 - 1) WRITEK(cur ^ 1);  // stage next tile (after compute)
  }

  float linv = 1.0f / lrow;
  size_t rowb = ((size_t)b * S + q0 + lq) * D + (size_t)h * HD;
#pragma unroll
  for (int hdsub = 0; hdsub < 2; ++hdsub)
#pragma unroll
    for (int rr = 0; rr < 4; ++rr) {
      f32x4 o = { oaccT[hdsub][rr * 4 + 0] * linv, oaccT[hdsub][rr * 4 + 1] * linv,
                  oaccT[hdsub][rr * 4 + 2] * linv, oaccT[hdsub][rr * 4 + 3] * linv };
      *(f32x4*)(ctx + rowb + 32 * hdsub + 8 * rr + 4 * hi) = o;
    }
}

// ---------------- LayerNorms (bf16 in/out where possible) ----------------

DEV void block_stats(float s, float s2, float* red, int tid, float& mu, float& rstd) {
  for (int off = 32; off > 0; off >>= 1) {
    s += __shfl_down(s, off);
    s2 += __shfl_down(s2, off);
  }
  int wave = tid >> 6, lane = tid & 63;
  if (lane == 0) { red[wave] = s; red[4 + wave] = s2; }
  __syncthreads();
  float S1 = red[0] + red[1] + red[2] + red[3];
  float S2 = red[4] + red[5] + red[6] + red[7];
  mu = S1 * (1.f / 1024.f);
  rstd = rsqrtf(S2 * (1.f / 1024.f) - mu * mu + 1e-5f);
}

// LN0: x = qb*INVQSCALE + ctx; out ob (bf16)
__global__ __launch_bounds__(256) void ln0_kernel(
    const bf16* __restrict__ qb, const float* __restrict__ ctx,
    const float* __restrict__ g, const float* __restrict__ beta,
    bf16* __restrict__ ob)
{
  __shared__ float red[8];
  const int row = blockIdx.x, tid = threadIdx.x;
  const size_t base = (size_t)row * D;
  bf16x4 qv = *(const bf16x4*)(qb + base + tid * 4);
  float4 c = *(const float4*)(ctx + base + tid * 4);
  float x0 = (float)qv[0] * INVQSCALE + c.x;
  float x1 = (float)qv[1] * INVQSCALE + c.y;
  float x2 = (float)qv[2] * INVQSCALE + c.z;
  float x3 = (float)qv[3] * INVQSCALE + c.w;
  float mu, rstd;
  block_stats(x0 + x1 + x2 + x3,
              x0 * x0 + x1 * x1 + x2 * x2 + x3 * x3, red, tid, mu, rstd);
  float4 gv = *(const float4*)(g + tid * 4);
  float4 bv = *(const float4*)(beta + tid * 4);
  bf16x4 o = { (bf16)((x0 - mu) * rstd * gv.x + bv.x),
               (bf16)((x1 - mu) * rstd * gv.y + bv.y),
               (bf16)((x2 - mu) * rstd * gv.z + bv.z),
               (bf16)((x3 - mu) * rstd * gv.w + bv.w) };
  *(bf16x4*)(ob + base + tid * 4) = o;
}

DEV float gelu_exact(float t) { return 0.5f * t * (1.f + erff(t * 0.70710678118654752f)); }

// LN1: x = ob + gelu(pb); out f32
__global__ __launch_bounds__(256) void ln1_kernel(
    const bf16* __restrict__ ob, const bf16* __restrict__ pb,
    const float* __restrict__ g, const float* __restrict__ beta,
    float* __restrict__ out)
{
  __shared__ float red[8];
  const int row = blockIdx.x, tid = threadIdx.x;
  const size_t base = (size_t)row * D;
  bf16x4 ov = *(const bf16x4*)(ob + base + tid * 4);
  bf16x4 pv = *(const bf16x4*)(pb + base + tid * 4);
  float x0 = (float)ov[0] + gelu_exact((float)pv[0]);
  float x1 = (float)ov[1] + gelu_exact((float)pv[1]);
  float x2 = (float)ov[2] + gelu_exact((float)pv[2]);
  float x3 = (float)ov[3] + gelu_exact((float)pv[3]);
  float mu, rstd;
  block_stats(x0 + x1 + x2 + x3,
              x0 * x0 + x1 * x1 + x2 * x2 + x3 * x3, red, tid, mu, rstd);
  float4 gv = *(const float4*)(g + tid * 4);
  float4 bv = *(const float4*)(beta + tid * 4);
  float o0 = (x0 - mu) * rstd * gv.x + bv.x;
  float o1 = (x1 - mu) * rstd * gv.y + bv.y;
  float o2 = (x2 - mu) * rstd * gv.z + bv.z;
  float o3 = (x3 - mu) * rstd * gv.w + bv.w;
  *(float4*)(out + base + tid * 4) = make_float4(o0, o1, o2, o3);
}

// ---------------- launch ----------------

extern "C" void kernel_launch(void* const* d_in, const int* in_sizes, int n_in,
                              void* d_out, int out_size, void* d_ws, size_t ws_size,
                              hipStream_t stream) {
  const float* Q     = (const float*)d_in[0];
  const float* K     = (const float*)d_in[1];
  const int*   mask  = (const int*)d_in[2];
  const float* Wq    = (const float*)d_in[3];
  const float* bq    = (const float*)d_in[4];
  const float* Wk    = (const float*)d_in[5];
  const float* bk    = (const float*)d_in[6];
  const float* Wv    = (const float*)d_in[7];
  const float* bv    = (const float*)d_in[8];
  const float* Wp    = (const float*)d_in[9];
  const float* bp    = (const float*)d_in[10];
  const float* g0    = (const float*)d_in[11];
  const float* beta0 = (const float*)d_in[12];
  const float* g1    = (const float*)d_in[13];
  const float* beta1 = (const float*)d_in[14];
  float* out = (float*)d_out;

  char* w = (char*)d_ws;
  const size_t MB = 1u << 20;
  bf16* Qb  = (bf16*)(w + 0 * MB);     // dead after gemm_qkv
  bf16* Kb  = (bf16*)(w + 16 * MB);
  bf16* Wqt = (bf16*)(w + 32 * MB);
  bf16* Wkt = (bf16*)(w + 34 * MB);
  bf16* Wvt = (bf16*)(w + 36 * MB);
  bf16* Wpt = (bf16*)(w + 38 * MB);
  bf16* qb  = (bf16*)(w + 40 * MB);
  bf16* kb  = (bf16*)(w + 56 * MB);
  bf16* vb  = (bf16*)(w + 72 * MB);
  float* ctx = (float*)(w + 88 * MB);  // 32MB f32
  bf16* pb  = (bf16*)(w + 120 * MB);
  bf16* ob  = (bf16*)(w + 0 * MB);     // alias Qb

  dim3 cg(1024, 2);
  cvt_bf16_kernel<<<cg, 256, 0, stream>>>(Q, Qb, K, Kb, M * D);
  dim3 tb(32, 8), tg(32, 32, 4);
  transpose_cvt_kernel<<<tg, tb, 0, stream>>>(Wq, Wqt, Wk, Wkt, Wv, Wvt, Wp, Wpt);

  dim3 gq(8, 64, 3);
  gemm_qkv_kernel<<<gq, 256, 0, stream>>>(Qb, Kb, Wqt, Wkt, Wvt, bq, bk, bv, qb, kb, vb);

  attn_kernel<<<1024, 256, 0, stream>>>(qb, kb, vb, mask, ctx);

  ln0_kernel<<<M, 256, 0, stream>>>(qb, ctx, g0, beta0, ob);
  dim3 gp(8, 64);
  gemm_p_kernel<<<gp, 256, 0, stream>>>(ob, Wpt, bp, pb);
  ln1_kernel<<<M, 256, 0, stream>>>(ob, pb, g1, beta1, out);
}

// Round 10
// 321.749 us; speedup vs baseline: 1.3402x; 1.0590x over previous
//
#include <hip/hip_runtime.h>
#include <hip/hip_bf16.h>
#include <math.h>

#define DEV __device__ __forceinline__

typedef __bf16 bf16;
typedef __bf16 bf16x8 __attribute__((ext_vector_type(8)));
typedef __bf16 bf16x4 __attribute__((ext_vector_type(4)));
typedef __bf16 bf16x2 __attribute__((ext_vector_type(2)));
typedef float f32x4 __attribute__((ext_vector_type(4)));
typedef float f32x16 __attribute__((ext_vector_type(16)));
typedef int i32x2 __attribute__((ext_vector_type(2)));
typedef unsigned int u32;
typedef unsigned long long u64;

static constexpr int BATCH = 8, S = 1024, D = 1024, H = 16, HD = 64;
static constexpr int M = BATCH * S;

// 0.125 (1/sqrt(hd)) * log2(e): folded into qb so softmax runs in exp2 domain
static constexpr float QSCALE = 0.18033688f;
static constexpr float INVQSCALE = 5.54517744f;   // 1/QSCALE

DEV f32x4 mfma16(bf16x8 a, bf16x8 b, f32x4 c) {
  return __builtin_amdgcn_mfma_f32_16x16x32_bf16(a, b, c, 0, 0, 0);
}
DEV f32x16 mfma32(bf16x8 a, bf16x8 b, f32x16 c) {
  return __builtin_amdgcn_mfma_f32_32x32x16_bf16(a, b, c, 0, 0, 0);
}

DEV void gload_lds16(const void* g, void* l) {
  __builtin_amdgcn_global_load_lds(
      (__attribute__((address_space(1))) void*)(g),
      (__attribute__((address_space(3))) void*)(l), 16, 0, 0);
}

DEV bf16x8 lds_read8(const void* base, int byteoff) {
  return *(const bf16x8*)((const char*)base + byteoff);
}

DEV u32 packbf(float a, float b) {
  bf16x2 t = { (bf16)a, (bf16)b };
  return __builtin_bit_cast(u32, t);
}

// partner (lane^32) value via permlane32_swap (no LDS, unlike ds_bpermute)
DEV float xor32_val(float x, int hi) {
  int xi = __builtin_bit_cast(int, x);
  i32x2 r = __builtin_amdgcn_permlane32_swap(xi, xi, false, false);
  return __builtin_bit_cast(float, hi ? r[0] : r[1]);
}

// ---------------- elementwise converts (fused via grid.y) ----------------

__global__ void cvt_bf16_kernel(const float* __restrict__ in0, bf16* __restrict__ out0,
                                const float* __restrict__ in1, bf16* __restrict__ out1, int n) {
  const float* in = blockIdx.y ? in1 : in0;
  bf16* out = blockIdx.y ? out1 : out0;
  int i = (blockIdx.x * blockDim.x + threadIdx.x) * 4;
  int stride = gridDim.x * blockDim.x * 4;
  for (; i < n; i += stride) {
    float4 v = *(const float4*)(in + i);
    bf16x4 o = { (bf16)v.x, (bf16)v.y, (bf16)v.z, (bf16)v.w };
    *(bf16x4*)(out + i) = o;
  }
}

// W [K][N] f32 -> Wt [N][K] bf16; z selects which weight
__global__ void transpose_cvt_kernel(const float* __restrict__ w0, bf16* __restrict__ o0,
                                     const float* __restrict__ w1, bf16* __restrict__ o1,
                                     const float* __restrict__ w2, bf16* __restrict__ o2,
                                     const float* __restrict__ w3, bf16* __restrict__ o3) {
  const int z = blockIdx.z;
  const float* in = z == 0 ? w0 : z == 1 ? w1 : z == 2 ? w2 : w3;
  bf16* out = z == 0 ? o0 : z == 1 ? o1 : z == 2 ? o2 : o3;
  __shared__ float t[32][33];
  int n0 = blockIdx.x * 32, k0 = blockIdx.y * 32;
  int tx = threadIdx.x, ty = threadIdx.y;   // block (32,8)
  for (int i = 0; i < 32; i += 8)
    t[ty + i][tx] = in[(size_t)(k0 + ty + i) * D + n0 + tx];
  __syncthreads();
  for (int i = 0; i < 32; i += 8)
    out[(size_t)(n0 + ty + i) * D + k0 + tx] = (bf16)t[tx][ty + i];
}

// ---------------- GEMM body (m97 structure + XOR-swizzled LDS) ----------------
// TRANS=false: Cb[m][n] (token-major). TRANS=true: Cb[n][M + m] (feature-major,
// i.e. C^T) via swapped MFMA operands — used for V so attention can stage V^T
// with coalesced row loads instead of a scalar gather.

template<bool TRANS>
DEV void gemm_body(const bf16* A, const bf16* Bt, const float* bias,
                   bf16* Cb, float osc, bf16* As, bf16* Bs) {
  constexpr int K = 1024, N = 1024, BK = 32;
  const int tid = threadIdx.x, lane = tid & 63, wave = tid >> 6;
  const int lo = lane & 15, g = lane >> 4;
  int f = blockIdx.y * 8 + blockIdx.x;          // gridDim (8,64) -> 512
  f = (f & 7) * 64 + (f >> 3);                  // XCD-chunked, bijective
  const int bm = f >> 3, bn = f & 7;
  const int wr = wave >> 1, wc = wave & 1;
  f32x4 acc[4][4] = {};
  const char* Ab = (const char*)(A + (size_t)bm * 128 * K);
  const char* Bb = (const char*)(Bt + (size_t)bn * 128 * K);

  // staging geometry (swizzled source)
  const int srow[2] = { (wave * 2 + 0) * 16 + (lane >> 2), (wave * 2 + 1) * 16 + (lane >> 2) };
  const int sslot = lane & 3;

  for (int kt = 0; kt < K / BK; ++kt) {
    __syncthreads();
    const int k0b = kt * (BK * 2);
    for (int i = 0; i < 2; ++i) {
      int cbase = (wave * 2 + i) * 1024;
      int row = srow[i];
      int scol = ((sslot ^ (row & 3)) << 4);
      gload_lds16(Ab + (size_t)row * (K * 2) + k0b + scol, (char*)As + cbase);
      gload_lds16(Bb + (size_t)row * (K * 2) + k0b + scol, (char*)Bs + cbase);
    }
    __syncthreads();
    bf16x8 af[4], bfr[4];
    for (int mi = 0; mi < 4; ++mi) {
      int ar = wr * 64 + mi * 16 + lo;
      af[mi] = lds_read8(As, ar * 64 + ((g ^ (ar & 3)) << 4));
    }
    for (int ni = 0; ni < 4; ++ni) {
      int br = wc * 64 + ni * 16 + lo;
      bfr[ni] = lds_read8(Bs, br * 64 + ((g ^ (br & 3)) << 4));
    }
    for (int mi = 0; mi < 4; ++mi)
      for (int ni = 0; ni < 4; ++ni) {
        if (!TRANS) acc[mi][ni] = mfma16(af[mi], bfr[ni], acc[mi][ni]);
        else        acc[ni][mi] = mfma16(bfr[ni], af[mi], acc[ni][mi]);
      }
  }

  const int rbase = bm * 128 + wr * 64;   // m
  const int cbase = bn * 128 + wc * 64;   // n
  if (!TRANS) {
    for (int ni = 0; ni < 4; ++ni) {
      int col = cbase + ni * 16 + lo;
      float bv = bias[col];
      for (int mi = 0; mi < 4; ++mi) {
        int row0 = rbase + mi * 16 + g * 4;
        for (int r = 0; r < 4; ++r) {
          float v = acc[mi][ni][r] + bv;
          Cb[(size_t)(row0 + r) * N + col] = (bf16)(v * osc);
        }
      }
    }
  } else {
    // C^T: row = n (feature), col = m (token); lane col = lo (coalesced 32B)
    for (int ni = 0; ni < 4; ++ni)
      for (int r = 0; r < 4; ++r) {
        int n = cbase + ni * 16 + g * 4 + r;
        float bv = bias[n];
        for (int mi = 0; mi < 4; ++mi) {
          int m = rbase + mi * 16 + lo;
          Cb[(size_t)n * M + m] = (bf16)(acc[ni][mi][r] + bv);
        }
      }
  }
}

__global__ __launch_bounds__(256) void gemm_qkv_kernel(
    const bf16* __restrict__ Qb, const bf16* __restrict__ Kb,
    const bf16* __restrict__ Wqt, const bf16* __restrict__ Wkt, const bf16* __restrict__ Wvt,
    const float* __restrict__ bq, const float* __restrict__ bk, const float* __restrict__ bv,
    bf16* __restrict__ qb, bf16* __restrict__ kb, bf16* __restrict__ vbt)
{
  __shared__ bf16 As[128 * 32];
  __shared__ bf16 Bs[128 * 32];
  const int z = blockIdx.z;
  if (z == 0)      gemm_body<false>(Qb, Wqt, bq, qb, QSCALE, As, Bs);
  else if (z == 1) gemm_body<false>(Kb, Wkt, bk, kb, 1.f, As, Bs);
  else             gemm_body<true >(Kb, Wvt, bv, vbt, 1.f, As, Bs);
}

__global__ __launch_bounds__(256) void gemm_p_kernel(
    const bf16* __restrict__ A, const bf16* __restrict__ Bt,
    const float* __restrict__ bias, bf16* __restrict__ Cb)
{
  __shared__ bf16 As[128 * 32];
  __shared__ bf16 Bs[128 * 32];
  gemm_body<false>(A, Bt, bias, Cb, 1.f, As, Bs);
}

// ---------------- flash attention, 32x32 MFMA, no P-LDS ----------------
// V^T pre-materialized by the GEMM (vt[1024 features][8192 tokens]) so both K
// and V^T stage with coalesced b128 row loads into swizzled LDS.

DEV int swz(int row, int colb) { return row * 128 + (colb ^ ((row & 7) << 4)); }

__global__ __launch_bounds__(256, 3) void attn_kernel(
    const bf16* __restrict__ q, const bf16* __restrict__ k, const bf16* __restrict__ vt,
    const int* __restrict__ mask, float* __restrict__ ctx)
{
  __shared__ bf16 Kl[2][64 * 64];   // [kv][hd] swizzled
  __shared__ bf16 Vt[2][64 * 64];   // [hd][kv] swizzled
  const int tid = threadIdx.x, lane = tid & 63, wave = tid >> 6;
  const int hi = lane >> 5, lq = lane & 31;
  const int wg = blockIdx.x;
  const int xcd = wg & 7, ix = wg >> 3;
  const int bh = xcd * 16 + (ix & 15);
  const int qt = ix >> 4;                 // 0..7
  const int b = bh >> 4, h = bh & 15;
  const int q0 = qt * 128 + wave * 32;
  const size_t base = (size_t)b * S * D + (size_t)h * HD;

  bf16x8 qf[4];
#pragma unroll
  for (int hc = 0; hc < 4; ++hc)
    qf[hc] = *(const bf16x8*)(q + base + (size_t)(q0 + lq) * D + hc * 16 + hi * 8);

  f32x16 oaccT[2] = {};     // O^T[hd = (reg&3)+8*(reg>>2)+4*hi+32*hdsub][q=lq]
  float mrow = -3e38f, lrow = 0.f;

  bf16x8 kst[2], vst[2];
  const int koff = tid * 16;              // rows of 128B
  const int krow = koff >> 7, kcol = koff & 127;
  // V^T tile source: vt[h*64 + hd][b*1024 + kv0 + ...], row stride M tokens
  const bf16* vbase = vt + (size_t)(h * 64) * M + (size_t)b * S;

#define LOADKV(KV0)                                                             \
  {                                                                             \
    _Pragma("unroll")                                                           \
    for (int rr = 0; rr < 2; ++rr)                                              \
      kst[rr] = *(const bf16x8*)((const char*)(k + base +                       \
                 (size_t)((KV0) + rr * 32 + krow) * D) + kcol);                 \
    _Pragma("unroll")                                                           \
    for (int rr = 0; rr < 2; ++rr)                                              \
      vst[rr] = *(const bf16x8*)((const char*)(vbase +                          \
                 (size_t)(rr * 32 + krow) * M + (KV0)) + kcol);                 \
  }

#define WRITEKV(BI)                                                             \
  {                                                                             \
    _Pragma("unroll")                                                           \
    for (int rr = 0; rr < 2; ++rr)                                              \
      *(bf16x8*)((char*)Kl[BI] + swz(rr * 32 + krow, kcol)) = kst[rr];          \
    _Pragma("unroll")                                                           \
    for (int rr = 0; rr < 2; ++rr)                                              \
      *(bf16x8*)((char*)Vt[BI] + swz(rr * 32 + krow, kcol)) = vst[rr];          \
  }

  LOADKV(0);
  WRITEKV(0);

  for (int kt = 0; kt < S / 64; ++kt) {
    const int cur = kt & 1;
    const int kv0 = kt * 64;
    __syncthreads();                        // buf[cur] staged, buf[cur^1] free
    if (kt < S / 64 - 1) LOADKV(kv0 + 64);  // issue next-tile globals early

    const char* Kb_ = (const char*)Kl[cur];
    const char* Vb_ = (const char*)Vt[cur];

    u64 mv = __ballot(mask[b * S + kv0 + lane] != 0);

    f32x16 sacc[2];
    __builtin_amdgcn_s_setprio(1);
#pragma unroll
    for (int sub = 0; sub < 2; ++sub) {
      f32x16 a = {};
#pragma unroll
      for (int hc = 0; hc < 4; ++hc) {
        bf16x8 kf = lds_read8(Kb_, swz(sub * 32 + lq, hc * 32 + hi * 16));
        a = mfma32(kf, qf[hc], a);
      }
      sacc[sub] = a;
    }
    __builtin_amdgcn_s_setprio(0);

    float mx = -3e38f;
    if (mv == ~0ull) {
#pragma unroll
      for (int sub = 0; sub < 2; ++sub)
#pragma unroll
        for (int r = 0; r < 16; ++r) mx = fmaxf(mx, sacc[sub][r]);
    } else {
      u64 mqh = mv >> (hi * 4);
#pragma unroll
      for (int sub = 0; sub < 2; ++sub)
#pragma unroll
        for (int rr = 0; rr < 4; ++rr)
#pragma unroll
          for (int rm = 0; rm < 4; ++rm) {
            int reg = rr * 4 + rm;
            bool ok = (mqh >> (rm + 8 * rr + 32 * sub)) & 1ull;
            float s = ok ? sacc[sub][reg] : -1e30f;
            sacc[sub][reg] = s;
            mx = fmaxf(mx, s);
          }
    }
    mx = fmaxf(mx, xor32_val(mx, hi));

    if (__any(mx > mrow + 11.5f)) {
      float mnew = fmaxf(mrow, mx);
      float fsc = exp2f(mrow - mnew);
      mrow = mnew;
      lrow *= fsc;
      oaccT[0] *= fsc;
      oaccT[1] *= fsc;
    }

    float rs = 0.f;
    u32 W[2][4][2];
#pragma unroll
    for (int sub = 0; sub < 2; ++sub)
#pragma unroll
      for (int rr = 0; rr < 4; ++rr)
#pragma unroll
        for (int hh = 0; hh < 2; ++hh) {
          float p0 = exp2f(sacc[sub][rr * 4 + 2 * hh] - mrow);
          float p1 = exp2f(sacc[sub][rr * 4 + 2 * hh + 1] - mrow);
          rs += p0 + p1;
          W[sub][rr][hh] = packbf(p0, p1);
        }
    rs += xor32_val(rs, hi);
    lrow += rs;

    bf16x8 pfr[4];
#pragma unroll
    for (int t = 0; t < 4; ++t) {
      const int sub = t >> 1, r0 = 2 * (t & 1);
      i32x2 s0 = __builtin_amdgcn_permlane32_swap(
          (int)W[sub][r0][0], (int)W[sub][r0 + 1][0], false, false);
      i32x2 s1 = __builtin_amdgcn_permlane32_swap(
          (int)W[sub][r0][1], (int)W[sub][r0 + 1][1], false, false);
      u32 wd[4] = { (u32)s0[0], (u32)s1[0], (u32)s0[1], (u32)s1[1] };
      pfr[t] = __builtin_bit_cast(bf16x8, wd);
    }

    __builtin_amdgcn_s_setprio(1);
#pragma unroll
    for (int hdsub = 0; hdsub < 2; ++hdsub) {
      f32x16 a = oaccT[hdsub];
#pragma unroll
      for (int t = 0; t < 4; ++t) {
        bf16x8 vf = lds_read8(Vb_, swz(hdsub * 32 + lq, t * 32 + hi * 16));
        a = mfma32(vf, pfr[t], a);
      }
      oaccT[hdsub] = a;
    }
    __builtin_amdgcn_s_setprio(0);

    if (kt < S / 64 - 1) WRITEKV(cur ^ 1);  // stage next tile (after compute)
  }

  float linv = 1.0f / lrow;
  size_t rowb = ((size_t)b * S + q0 + lq) * D + (size_t)h * HD;
#pragma unroll
  for (int hdsub = 0; hdsub < 2; ++hdsub)
#pragma unroll
    for (int rr = 0; rr < 4; ++rr) {
      f32x4 o = { oaccT[hdsub][rr * 4 + 0] * linv, oaccT[hdsub][rr * 4 + 1] * linv,
                  oaccT[hdsub][rr * 4 + 2] * linv, oaccT[hdsub][rr * 4 + 3] * linv };
      *(f32x4*)(ctx + rowb + 32 * hdsub + 8 * rr + 4 * hi) = o;
    }
}

// ---------------- LayerNorms (bf16 in/out where possible) ----------------

DEV void block_stats(float s, float s2, float* red, int tid, float& mu, float& rstd) {
  for (int off = 32; off > 0; off >>= 1) {
    s += __shfl_down(s, off);
    s2 += __shfl_down(s2, off);
  }
  int wave = tid >> 6, lane = tid & 63;
  if (lane == 0) { red[wave] = s; red[4 + wave] = s2; }
  __syncthreads();
  float S1 = red[0] + red[1] + red[2] + red[3];
  float S2 = red[4] + red[5] + red[6] + red[7];
  mu = S1 * (1.f / 1024.f);
  rstd = rsqrtf(S2 * (1.f / 1024.f) - mu * mu + 1e-5f);
}

// LN0: x = qb*INVQSCALE + ctx; out ob (bf16)
__global__ __launch_bounds__(256) void ln0_kernel(
    const bf16* __restrict__ qb, const float* __restrict__ ctx,
    const float* __restrict__ g, const float* __restrict__ beta,
    bf16* __restrict__ ob)
{
  __shared__ float red[8];
  const int row = blockIdx.x, tid = threadIdx.x;
  const size_t base = (size_t)row * D;
  bf16x4 qv = *(const bf16x4*)(qb + base + tid * 4);
  float4 c = *(const float4*)(ctx + base + tid * 4);
  float x0 = (float)qv[0] * INVQSCALE + c.x;
  float x1 = (float)qv[1] * INVQSCALE + c.y;
  float x2 = (float)qv[2] * INVQSCALE + c.z;
  float x3 = (float)qv[3] * INVQSCALE + c.w;
  float mu, rstd;
  block_stats(x0 + x1 + x2 + x3,
              x0 * x0 + x1 * x1 + x2 * x2 + x3 * x3, red, tid, mu, rstd);
  float4 gv = *(const float4*)(g + tid * 4);
  float4 bv = *(const float4*)(beta + tid * 4);
  bf16x4 o = { (bf16)((x0 - mu) * rstd * gv.x + bv.x),
               (bf16)((x1 - mu) * rstd * gv.y + bv.y),
               (bf16)((x2 - mu) * rstd * gv.z + bv.z),
               (bf16)((x3 - mu) * rstd * gv.w + bv.w) };
  *(bf16x4*)(ob + base + tid * 4) = o;
}

DEV float gelu_exact(float t) { return 0.5f * t * (1.f + erff(t * 0.70710678118654752f)); }

// LN1: x = ob + gelu(pb); out f32
__global__ __launch_bounds__(256) void ln1_kernel(
    const bf16* __restrict__ ob, const bf16* __restrict__ pb,
    const float* __restrict__ g, const float* __restrict__ beta,
    float* __restrict__ out)
{
  __shared__ float red[8];
  const int row = blockIdx.x, tid = threadIdx.x;
  const size_t base = (size_t)row * D;
  bf16x4 ov = *(const bf16x4*)(ob + base + tid * 4);
  bf16x4 pv = *(const bf16x4*)(pb + base + tid * 4);
  float x0 = (float)ov[0] + gelu_exact((float)pv[0]);
  float x1 = (float)ov[1] + gelu_exact((float)pv[1]);
  float x2 = (float)ov[2] + gelu_exact((float)pv[2]);
  float x3 = (float)ov[3] + gelu_exact((float)pv[3]);
  float mu, rstd;
  block_stats(x0 + x1 + x2 + x3,
              x0 * x0 + x1 * x1 + x2 * x2 + x3 * x3, red, tid, mu, rstd);
  float4 gv = *(const float4*)(g + tid * 4);
  float4 bv = *(const float4*)(beta + tid * 4);
  float o0 = (x0 - mu) * rstd * gv.x + bv.x;
  float o1 = (x1 - mu) * rstd * gv.y + bv.y;
  float o2 = (x2 - mu) * rstd * gv.z + bv.z;
  float o3 = (x3 - mu) * rstd * gv.w + bv.w;
  *(float4*)(out + base + tid * 4) = make_float4(o0, o1, o2, o3);
}

// ---------------- launch ----------------

extern "C" void kernel_launch(void* const* d_in, const int* in_sizes, int n_in,
                              void* d_out, int out_size, void* d_ws, size_t ws_size,
                              hipStream_t stream) {
  const float* Q     = (const float*)d_in[0];
  const float* K     = (const float*)d_in[1];
  const int*   mask  = (const int*)d_in[2];
  const float* Wq    = (const float*)d_in[3];
  const float* bq    = (const float*)d_in[4];
  const float* Wk    = (const float*)d_in[5];
  const float* bk    = (const float*)d_in[6];
  const float* Wv    = (const float*)d_in[7];
  const float* bv    = (const float*)d_in[8];
  const float* Wp    = (const float*)d_in[9];
  const float* bp    = (const float*)d_in[10];
  const float* g0    = (const float*)d_in[11];
  const float* beta0 = (const float*)d_in[12];
  const float* g1    = (const float*)d_in[13];
  const float* beta1 = (const float*)d_in[14];
  float* out = (float*)d_out;

  char* w = (char*)d_ws;
  const size_t MB = 1u << 20;
  bf16* Qb  = (bf16*)(w + 0 * MB);     // dead after gemm_qkv
  bf16* Kb  = (bf16*)(w + 16 * MB);
  bf16* Wqt = (bf16*)(w + 32 * MB);
  bf16* Wkt = (bf16*)(w + 34 * MB);
  bf16* Wvt = (bf16*)(w + 36 * MB);
  bf16* Wpt = (bf16*)(w + 38 * MB);
  bf16* qb  = (bf16*)(w + 40 * MB);
  bf16* kb  = (bf16*)(w + 56 * MB);
  bf16* vbt = (bf16*)(w + 72 * MB);    // V^T [1024][8192]
  float* ctx = (float*)(w + 88 * MB);  // 32MB f32
  bf16* pb  = (bf16*)(w + 120 * MB);
  bf16* ob  = (bf16*)(w + 0 * MB);     // alias Qb

  dim3 cg(1024, 2);
  cvt_bf16_kernel<<<cg, 256, 0, stream>>>(Q, Qb, K, Kb, M * D);
  dim3 tb(32, 8), tg(32, 32, 4);
  transpose_cvt_kernel<<<tg, tb, 0, stream>>>(Wq, Wqt, Wk, Wkt, Wv, Wvt, Wp, Wpt);

  dim3 gq(8, 64, 3);
  gemm_qkv_kernel<<<gq, 256, 0, stream>>>(Qb, Kb, Wqt, Wkt, Wvt, bq, bk, bv, qb, kb, vbt);

  attn_kernel<<<1024, 256, 0, stream>>>(qb, kb, vbt, mask, ctx);

  ln0_kernel<<<M, 256, 0, stream>>>(qb, ctx, g0, beta0, ob);
  dim3 gp(8, 64);
  gemm_p_kernel<<<gp, 256, 0, stream>>>(ob, Wpt, bp, pb);
  ln1_kernel<<<M, 256, 0, stream>>>(ob, pb, g1, beta1, out);
}